// Round 13
// baseline (164.324 us; speedup 1.0000x reference)
//
#include <hip/hip_runtime.h>

// All tensors float32. Math structure exploited:
//  - softmax over axis of size 1 == 1.0 -> attn all-ones, Wa/ba dead.
//  - weighted = row-sum of tanh(agg), broadcast over COLUMNS (N==D quirk).
//  - lig_p = nf@Wl.T + const  ->  x0[h,i,j] = PL[i,h] + PR[j,h] + c[h]
//  - conv1 is LINEAR in rank-structured x0: y1_pre = U[xc][y] + V[yc][x] + K'.
//    conv stages ys = relu(U+V+K'); conv2+conv3 on f16 MFMA.
//  - ROUND-13: launches 4 -> 3 (~12us/launch measured across rounds 10-12).
//    PL/PR never materialized: proj+uv fused (each block computes its 8 rows'
//    P-dots + 2 halo rows in LDS, applies the 3-case 1D conv, writes U16/V16).
//    cveck + w2pack ride the same grid as extra roles. gnn and conv kernels
//    byte-identical to round 12 (proven; round-11 lesson: don't perturb gnn).

typedef _Float16 half8 __attribute__((ext_vector_type(8)));
typedef _Float16 half4 __attribute__((ext_vector_type(4)));
typedef float    f32x4 __attribute__((ext_vector_type(4)));

__device__ __forceinline__ short f2h_bits(float f){
    _Float16 h = (_Float16)f;          // RNE
    return __builtin_bit_cast(short, h);
}
__device__ __forceinline__ half8 pack2(const float4& x, const float4& y){
    half8 r;
    r[0] = (_Float16)x.x; r[1] = (_Float16)x.y;
    r[2] = (_Float16)x.z; r[3] = (_Float16)x.w;
    r[4] = (_Float16)y.x; r[5] = (_Float16)y.y;
    r[6] = (_Float16)y.z; r[7] = (_Float16)y.w;
    return r;
}
__device__ __forceinline__ float tanh_fast(float x){
    float e = __expf(2.f * x);
    return 1.f - 2.f / (e + 1.f);
}

// ci-block swizzle for conv LDS tiles (round-4 verified layout)
#define SWZ(c) ((((c) >> 1) & 3) << 3)

// ---------------------------------------------------------------------------
// K1 (MFMA): agg = tanh([nf|ef]@[Wn|We].T + bn + be); per-block row-sums ->
// part[cx][dblk][row]. BM=128, BN=64, BK=64, 512 thr, register prefetch.
// grid (8,16,2). (round-12 verbatim)
// ---------------------------------------------------------------------------
__global__ __launch_bounds__(512) void gnn_kernel(
    const float* __restrict__ lig_nf, const float* __restrict__ lig_ef,
    const float* __restrict__ rec_nf, const float* __restrict__ rec_ef,
    const float* __restrict__ Wn, const float* __restrict__ We,
    const float* __restrict__ bn, const float* __restrict__ be,
    float* __restrict__ part)   // [2][16][1024]
{
    __shared__ __attribute__((aligned(16))) short As[128 * 64];
    __shared__ __attribute__((aligned(16))) short Bs[64 * 64];
    __shared__ float red[128][2];

    const int t  = threadIdx.x;
    const int cx = blockIdx.z;
    const float* A0 = cx ? rec_nf : lig_nf;
    const float* A1 = cx ? rec_ef : lig_ef;
    const int j0 = blockIdx.x * 128;
    const int d0 = blockIdx.y * 64;

    const int wid  = t >> 6;
    const int wm   = wid >> 1;
    const int wn   = wid & 1;
    const int lane = t & 63;
    const int lr   = lane & 15;
    const int lg   = lane >> 4;

    f32x4 acc[2][2];
    #pragma unroll
    for (int m = 0; m < 2; ++m)
        #pragma unroll
        for (int n = 0; n < 2; ++n)
            acc[m][n] = (f32x4){0.f, 0.f, 0.f, 0.f};

    const int arow = t >> 2;
    const int akc  = (t & 3) * 16;
    const int brow = t >> 3;
    const int bkc  = (t & 7) * 8;

    float4 av[4], bv[2];
    {
        const float* ap = A0 + (size_t)(j0 + arow) * 1024 + akc;
        const float* bp = Wn + (size_t)(d0 + brow) * 1024 + bkc;
        #pragma unroll
        for (int q = 0; q < 4; ++q) av[q] = *reinterpret_cast<const float4*>(ap + q * 4);
        #pragma unroll
        for (int q = 0; q < 2; ++q) bv[q] = *reinterpret_cast<const float4*>(bp + q * 4);
    }

    for (int kb = 0; kb < 2048; kb += 64){
        __syncthreads();
        {
            const int ga = (t & 3) * 2;
            const int sa = arow & 7;
            *reinterpret_cast<half8*>(&As[arow * 64 + ((ga    ) ^ sa) * 8]) = pack2(av[0], av[1]);
            *reinterpret_cast<half8*>(&As[arow * 64 + ((ga + 1) ^ sa) * 8]) = pack2(av[2], av[3]);
            *reinterpret_cast<half8*>(&Bs[brow * 64 + (((t & 7)) ^ (brow & 7)) * 8]) = pack2(bv[0], bv[1]);
        }
        {
            const int kbn = (kb + 64) & 2047;
            const float* Asrc = (kbn < 1024) ? A0 : A1;
            const float* Bsrc = (kbn < 1024) ? Wn : We;
            const int kk = kbn & 1023;
            const float* ap = Asrc + (size_t)(j0 + arow) * 1024 + kk + akc;
            const float* bp = Bsrc + (size_t)(d0 + brow) * 1024 + kk + bkc;
            #pragma unroll
            for (int q = 0; q < 4; ++q) av[q] = *reinterpret_cast<const float4*>(ap + q * 4);
            #pragma unroll
            for (int q = 0; q < 2; ++q) bv[q] = *reinterpret_cast<const float4*>(bp + q * 4);
        }
        __syncthreads();

        #pragma unroll
        for (int ks = 0; ks < 2; ++ks){
            half8 Af[2], Bf[2];
            #pragma unroll
            for (int m = 0; m < 2; ++m){
                int row = wm * 32 + m * 16 + lr;
                int g   = ((ks * 4 + lg) ^ (row & 7)) * 8;
                Af[m] = *reinterpret_cast<const half8*>(&As[row * 64 + g]);
            }
            #pragma unroll
            for (int n = 0; n < 2; ++n){
                int col = wn * 32 + n * 16 + lr;
                int g   = ((ks * 4 + lg) ^ (col & 7)) * 8;
                Bf[n] = *reinterpret_cast<const half8*>(&Bs[col * 64 + g]);
            }
            #pragma unroll
            for (int m = 0; m < 2; ++m)
                #pragma unroll
                for (int n = 0; n < 2; ++n)
                    acc[m][n] = __builtin_amdgcn_mfma_f32_16x16x32_f16(
                        Af[m], Bf[n], acc[m][n], 0, 0, 0);
        }
    }

    float rowsum[2][4];
    #pragma unroll
    for (int m = 0; m < 2; ++m)
        #pragma unroll
        for (int jj = 0; jj < 4; ++jj) rowsum[m][jj] = 0.f;
    #pragma unroll
    for (int n = 0; n < 2; ++n){
        int d = d0 + wn * 32 + n * 16 + lr;
        float bias = bn[d] + be[d];
        #pragma unroll
        for (int m = 0; m < 2; ++m)
            #pragma unroll
            for (int jj = 0; jj < 4; ++jj)
                rowsum[m][jj] += tanh_fast(acc[m][n][jj] + bias);
    }
    #pragma unroll
    for (int mask = 1; mask < 16; mask <<= 1)
        #pragma unroll
        for (int m = 0; m < 2; ++m)
            #pragma unroll
            for (int jj = 0; jj < 4; ++jj)
                rowsum[m][jj] += __shfl_xor(rowsum[m][jj], mask);
    __syncthreads();
    if (lr == 0){
        #pragma unroll
        for (int m = 0; m < 2; ++m)
            #pragma unroll
            for (int jj = 0; jj < 4; ++jj)
                red[wm * 32 + m * 16 + lg * 4 + jj][wn] = rowsum[m][jj];
    }
    __syncthreads();
    if (t < 128)
        part[(size_t)cx * 16384 + (size_t)blockIdx.y * 1024 + j0 + t]
            = red[t][0] + red[t][1];
}

// ---------------------------------------------------------------------------
// K2: projprep. grid 258 x 256 thr.
//  roles 0..255 : fused proj+uv. cx = role>>7 (0: lig->U16, 1: rec->V16),
//                 yb = role&127 -> 8 output rows. Computes 10 P-rows (8 + 2
//                 halo; 25% redundant dots) in LDS, then the 3-case 1D conv.
//  role 256     : cveck (w1 staged in LDS, unrolled taps) -> Kp
//  role 257     : w2pack -> f16 swizzled image for conv's LDS copy
// ---------------------------------------------------------------------------
__global__ __launch_bounds__(256) void projprep_kernel(
    const float* __restrict__ lig_nf, const float* __restrict__ rec_nf,
    const float* __restrict__ W_hopi, const float* __restrict__ b_hopi,
    const float* __restrict__ w1, const float* __restrict__ b1,
    const float* __restrict__ w2,
    const float* __restrict__ part,
    float* __restrict__ Kp, short* __restrict__ U16, short* __restrict__ V16,
    short* __restrict__ w2f16)
{
    __shared__ __attribute__((aligned(16))) char smem[46208];
    const int t = threadIdx.x;
    const int role = blockIdx.x;

    if (role < 256){
        // ---------------- fused proj+uv role ----------------
        float* Ws = reinterpret_cast<float*>(smem);            // [3][3][32][32] = 36864 B
        float* Pz = reinterpret_cast<float*>(smem + 36864);    // [10][32] = 1280 B
        const int cx = role >> 7;
        const int yb = role & 127;
        const int y0 = yb * 8;
        const float* nf = cx ? rec_nf : lig_nf;
        const float* W  = W_hopi + (cx ? 1024 : 0);
        short* O = cx ? V16 : U16;

        // stage Ws[cs][d][ci][co]: tap-subset sums of w1
        for (int e = t; e < 9216; e += 256){
            int co = e & 31;
            int ci = (e >> 5) & 31;
            int dc = e >> 10;               // cs*3 + d
            int cs = dc / 3;
            int d  = dc - cs * 3;
            int o_lo = (cs == 1) ? 1 : 0;
            int o_hi = (cs == 2) ? 1 : 2;
            float s = 0.f;
            for (int o = o_lo; o <= o_hi; ++o){
                int tap = cx ? (o * 3 + d) : (d * 3 + o);
                s += w1[co * 288 + ci * 9 + tap];
            }
            Ws[e] = s;
        }
        // phase A: P rows y0-1 .. y0+8 (10 rows x 32 h)
        {
            const int h  = t & 31;
            const int rs = t >> 5;          // 0..7
            const float* wrow = W + (size_t)h * 2048;
            for (int r = rs; r < 10; r += 8){
                int row = y0 - 1 + r;
                float s = 0.f;
                if (row >= 0 && row < 1024){
                    const float* nrow = nf + (size_t)row * 1024;
                    float s0 = 0.f, s1 = 0.f;
                    #pragma unroll 4
                    for (int j = 0; j < 1024; j += 8){
                        float4 a0 = *reinterpret_cast<const float4*>(nrow + j);
                        float4 b0 = *reinterpret_cast<const float4*>(wrow + j);
                        float4 a1 = *reinterpret_cast<const float4*>(nrow + j + 4);
                        float4 b1 = *reinterpret_cast<const float4*>(wrow + j + 4);
                        s0 = fmaf(a0.x, b0.x, s0); s0 = fmaf(a0.y, b0.y, s0);
                        s0 = fmaf(a0.z, b0.z, s0); s0 = fmaf(a0.w, b0.w, s0);
                        s1 = fmaf(a1.x, b1.x, s1); s1 = fmaf(a1.y, b1.y, s1);
                        s1 = fmaf(a1.z, b1.z, s1); s1 = fmaf(a1.w, b1.w, s1);
                    }
                    s = s0 + s1;
                }
                Pz[r * 32 + h] = s;
            }
        }
        __syncthreads();
        // phase B: U/V[cs][y][co] for 8 rows x 3 cases
        {
            const int co   = t & 31;
            const int slot = t >> 5;        // 0..7 -> output row y0+slot
            const int y = y0 + slot;
            #pragma unroll
            for (int cs = 0; cs < 3; ++cs){
                float acc = 0.f;
                #pragma unroll
                for (int d = 0; d < 3; ++d){
                    const float* p  = &Pz[(slot + d) * 32];
                    const float* ws = &Ws[(cs * 3 + d) * 1024 + co];
                    #pragma unroll
                    for (int ci = 0; ci < 32; ++ci)
                        acc = fmaf(p[ci], ws[ci * 32], acc);
                }
                O[((size_t)(cs << 10) + y) * 32 + co] = f2h_bits(acc);
            }
        }
        return;
    }

    if (role == 257){
        // ---------------- w2pack role ----------------
        for (int e = t; e < 9216; e += 256){
            int co  = e / 288;
            int rem = e - co * 288;
            int ci  = rem / 9;
            int tap = rem - ci * 9;
            w2f16[(tap * 32 + co) * 32 + (ci ^ SWZ(co))] = f2h_bits(w2[e]);
        }
        return;
    }

    // ---------------- cveck role (round-12 verbatim) ----------------
    float* ws_l = reinterpret_cast<float*>(smem);
    float* ws_r = reinterpret_cast<float*>(smem + 4096);
    float* red  = reinterpret_cast<float*>(smem + 8192);
    float* cvs  = reinterpret_cast<float*>(smem + 9216);
    float* w1s  = reinterpret_cast<float*>(smem + 9344);

    #pragma unroll
    for (int q = 0; q < 9; ++q){
        int idx = (t + q * 256) * 4;
        *reinterpret_cast<float4*>(&w1s[idx]) =
            *reinterpret_cast<const float4*>(w1 + idx);
    }
    for (int j = t; j < 1024; j += 256){
        float sl = 0.f, sr = 0.f;
        #pragma unroll
        for (int b = 0; b < 16; ++b){
            sl += part[b * 1024 + j];
            sr += part[16384 + b * 1024 + j];
        }
        ws_l[j] = sl; ws_r[j] = sr;
    }
    __syncthreads();
    {
        const int h = t & 31;
        const int seg = t >> 5;
        const float* wl = W_hopi + (size_t)h * 2048 + seg * 128;
        const float* wr = wl + 1024;
        float s = 0.f;
        #pragma unroll 8
        for (int j = 0; j < 128; j += 4){
            float4 a = *reinterpret_cast<const float4*>(wl + j);
            float4 b = *reinterpret_cast<const float4*>(wr + j);
            const float* l = &ws_l[seg * 128 + j];
            const float* r = &ws_r[seg * 128 + j];
            s = fmaf(l[0], a.x, s); s = fmaf(l[1], a.y, s);
            s = fmaf(l[2], a.z, s); s = fmaf(l[3], a.w, s);
            s = fmaf(r[0], b.x, s); s = fmaf(r[1], b.y, s);
            s = fmaf(r[2], b.z, s); s = fmaf(r[3], b.w, s);
        }
        red[t] = s;
    }
    __syncthreads();
    if (t < 32){
        float tot = b_hopi[t];
        #pragma unroll
        for (int g = 0; g < 8; ++g) tot += red[g * 32 + t];
        cvs[t] = tot;
    }
    __syncthreads();
    for (int e = t; e < 288; e += 256){
        int co  = e & 31;
        int cse = e >> 5;
        int yc  = cse / 3, xc = cse - yc * 3;
        float sum = b1[co];
        for (int ci = 0; ci < 32; ++ci){
            const float* wp = &w1s[co * 288 + ci * 9];
            float t00 = wp[0], t01 = wp[1], t02 = wp[2];
            float t10 = wp[3], t11 = wp[4], t12 = wp[5];
            float t20 = wp[6], t21 = wp[7], t22 = wp[8];
            float r0, r1, r2;
            if (xc == 0){ r0 = t00+t01+t02; r1 = t10+t11+t12; r2 = t20+t21+t22; }
            else if (xc == 1){ r0 = t01+t02; r1 = t11+t12; r2 = t21+t22; }
            else { r0 = t00+t01; r1 = t10+t11; r2 = t20+t21; }
            float wsum = (yc == 0) ? (r0+r1+r2) : ((yc == 1) ? (r1+r2) : (r0+r1));
            sum = fmaf(cvs[ci], wsum, sum);
        }
        Kp[cse * 32 + co] = sum;
    }
}

// ---------------------------------------------------------------------------
// K3: stage ys = relu(U+V+K'), wB by uint4 copy of prepacked w2f16, then
// conv2+relu+conv3 on f16 MFMA. LDS = 39,168 B. block 512, grid 64x64.
// (round-12 verbatim)
// ---------------------------------------------------------------------------
__global__ __launch_bounds__(512) void conv_kernel(
    const short* __restrict__ U16, const short* __restrict__ V16,
    const float* __restrict__ Kp, const short* __restrict__ w2f16,
    const float* __restrict__ b2,
    const float* __restrict__ w3, const float* __restrict__ b3,
    float* __restrict__ outp)
{
    __shared__ __attribute__((aligned(16))) short ys[18 * 18 * 32];
    __shared__ __attribute__((aligned(16))) short wB[9 * 32 * 32];

    const int t    = threadIdx.x;
    const int oy0  = blockIdx.y * 16;
    const int ox0  = blockIdx.x * 16;
    const int wid  = t >> 6;
    const int lane = t & 63;
    const int lr   = lane & 15;
    const int lg   = lane >> 4;

    {
        const uint4* src = reinterpret_cast<const uint4*>(w2f16);
        uint4* dst = reinterpret_cast<uint4*>(wB);
        #pragma unroll
        for (int e = t; e < 1152; e += 512)
            dst[e] = src[e];
    }
    #pragma unroll
    for (int pass = 0; pass < 6; ++pass){
        int idx = t + pass * 512;
        if (idx < 2592){
            int po  = idx >> 3;
            int cp  = (idx & 7) * 4;
            int ryo = po / 18;
            int rxo = po - ryo * 18;
            int gy = oy0 - 1 + ryo, gx = ox0 - 1 + rxo;
            half4 h = {(_Float16)0.f, (_Float16)0.f, (_Float16)0.f, (_Float16)0.f};
            if ((unsigned)gy < 1024u && (unsigned)gx < 1024u){
                int yc = (gy == 0) ? 1 : ((gy == 1023) ? 2 : 0);
                int xc = (gx == 0) ? 1 : ((gx == 1023) ? 2 : 0);
                half4 u = *reinterpret_cast<const half4*>(
                    &U16[((size_t)(xc << 10) + gy) * 32 + cp]);
                half4 v = *reinterpret_cast<const half4*>(
                    &V16[((size_t)(yc << 10) + gx) * 32 + cp]);
                float4 k = *reinterpret_cast<const float4*>(&Kp[(yc * 3 + xc) * 32 + cp]);
                h[0] = (_Float16)fmaxf((float)u[0] + (float)v[0] + k.x, 0.f);
                h[1] = (_Float16)fmaxf((float)u[1] + (float)v[1] + k.y, 0.f);
                h[2] = (_Float16)fmaxf((float)u[2] + (float)v[2] + k.z, 0.f);
                h[3] = (_Float16)fmaxf((float)u[3] + (float)v[3] + k.w, 0.f);
            }
            *reinterpret_cast<half4*>(&ys[po * 32 + (cp ^ SWZ(rxo))]) = h;
        }
    }
    __syncthreads();

    {
        half8 Bf[2][9];
        float bias[2], w3v[2];
        #pragma unroll
        for (int n = 0; n < 2; ++n){
            int co = n * 16 + lr;
            bias[n] = b2[co];
            w3v[n]  = w3[co];
            #pragma unroll
            for (int tap = 0; tap < 9; ++tap)
                Bf[n][tap] = *reinterpret_cast<const half8*>(
                    &wB[(tap * 32 + co) * 32 + ((lg * 8) ^ SWZ(co))]);
        }
        const float b3v = b3[0];
        for (int s = wid; s < 16; s += 8){
            int p  = s * 16 + lr;
            int ry = p >> 4;
            int rx = p & 15;
            f32x4 acc0 = {0.f, 0.f, 0.f, 0.f};
            f32x4 acc1 = {0.f, 0.f, 0.f, 0.f};
            #pragma unroll
            for (int tap = 0; tap < 9; ++tap){
                const int dy = tap / 3, dx = tap - (tap / 3) * 3;
                int pix = (ry + dy) * 18 + rx + dx;
                half8 A = *reinterpret_cast<const half8*>(
                    &ys[pix * 32 + ((lg * 8) ^ SWZ(rx + dx))]);
                acc0 = __builtin_amdgcn_mfma_f32_16x16x32_f16(A, Bf[0][tap], acc0, 0, 0, 0);
                acc1 = __builtin_amdgcn_mfma_f32_16x16x32_f16(A, Bf[1][tap], acc1, 0, 0, 0);
            }
            float part[4];
            #pragma unroll
            for (int j = 0; j < 4; ++j)
                part[j] = w3v[0] * fmaxf(acc0[j] + bias[0], 0.f)
                        + w3v[1] * fmaxf(acc1[j] + bias[1], 0.f);
            #pragma unroll
            for (int m = 1; m < 16; m <<= 1)
                #pragma unroll
                for (int j = 0; j < 4; ++j)
                    part[j] += __shfl_xor(part[j], m);
            if (lr == 0){
                float4 o = make_float4(part[0] + b3v, part[1] + b3v,
                                       part[2] + b3v, part[3] + b3v);
                *reinterpret_cast<float4*>(outp + (size_t)(oy0 + s) * 1024 + ox0 + lg * 4) = o;
            }
        }
    }
}

// ---------------------------------------------------------------------------
extern "C" void kernel_launch(void* const* d_in, const int* in_sizes, int n_in,
                              void* d_out, int out_size, void* d_ws, size_t ws_size,
                              hipStream_t stream)
{
    const float* lig_nf = (const float*)d_in[0];
    const float* lig_ef = (const float*)d_in[1];
    const float* rec_nf = (const float*)d_in[3];
    const float* rec_ef = (const float*)d_in[4];
    const float* Wn     = (const float*)d_in[6];
    const float* bn     = (const float*)d_in[7];
    const float* We     = (const float*)d_in[8];
    const float* be     = (const float*)d_in[9];
    const float* W_hopi = (const float*)d_in[12];
    const float* b_hopi = (const float*)d_in[13];
    const float* w1     = (const float*)d_in[14];
    const float* b1     = (const float*)d_in[15];
    const float* w2     = (const float*)d_in[16];
    const float* b2     = (const float*)d_in[17];
    const float* w3     = (const float*)d_in[18];
    const float* b3     = (const float*)d_in[19];
    float* outp = (float*)d_out;

    float* part  = (float*)d_ws;                              // [2][16][1024] f32
    float* Kp    = (float*)((char*)d_ws + 393216);            // 3*3*32 f32
    short* U16   = (short*)((char*)d_ws + 394368);            // 3*1024*32 f16
    short* V16   = (short*)((char*)d_ws + 590976);            // 3*1024*32 f16
    short* w2f16 = (short*)((char*)d_ws + 787584);            // 9216 f16 swizzled

    dim3 g1(8, 16, 2);
    gnn_kernel<<<g1, 512, 0, stream>>>(lig_nf, lig_ef, rec_nf, rec_ef,
                                       Wn, We, bn, be, part);
    projprep_kernel<<<258, 256, 0, stream>>>(lig_nf, rec_nf, W_hopi, b_hopi,
                                             w1, b1, w2, part,
                                             Kp, U16, V16, w2f16);
    dim3 g3(64, 64);
    conv_kernel<<<g3, 512, 0, stream>>>(U16, V16, Kp, w2f16, b2, w3, b3, outp);
}

// Round 14
// 124.059 us; speedup vs baseline: 1.3246x; 1.3246x over previous
//
#include <hip/hip_runtime.h>

// All tensors float32. Math structure exploited:
//  - softmax over axis of size 1 == 1.0 -> attn all-ones, Wa/ba dead.
//  - weighted = row-sum of tanh(agg), broadcast over COLUMNS (N==D quirk).
//  - lig_p = nf@Wl.T + const  ->  x0[h,i,j] = PL[i,h] + PR[j,h] + c[h]
//  - conv1 is LINEAR in rank-structured x0: y1_pre = U[xc][y] + V[yc][x] + K'.
//    conv stages ys = relu(U+V+K'); conv2+conv3 on f16 MFMA.
//  - ROUND-14: round-13 diagnosis -- proj's W reads were 64-lines-per-load
//    (lane h reads W[h*2048+j]); ~27us/CU of line-issue. pp_kernel replaces
//    proj+uv+cveck+w2pack: P via MFMA GEMM (coalesced staging, 80-row tile
//    incl. halo), uv via a second tiny MFMA GEMM (K=96), U16/V16 written
//    directly. 34 blocks, ~5us. gnn/conv = round-12 verbatim. 3 launches.

typedef _Float16 half8 __attribute__((ext_vector_type(8)));
typedef _Float16 half4 __attribute__((ext_vector_type(4)));
typedef float    f32x4 __attribute__((ext_vector_type(4)));

__device__ __forceinline__ short f2h_bits(float f){
    _Float16 h = (_Float16)f;          // RNE
    return __builtin_bit_cast(short, h);
}
__device__ __forceinline__ half8 pack2(const float4& x, const float4& y){
    half8 r;
    r[0] = (_Float16)x.x; r[1] = (_Float16)x.y;
    r[2] = (_Float16)x.z; r[3] = (_Float16)x.w;
    r[4] = (_Float16)y.x; r[5] = (_Float16)y.y;
    r[6] = (_Float16)y.z; r[7] = (_Float16)y.w;
    return r;
}
__device__ __forceinline__ float tanh_fast(float x){
    float e = __expf(2.f * x);
    return 1.f - 2.f / (e + 1.f);
}

// ci-block swizzle for conv LDS tiles (round-4 verified layout)
#define SWZ(c) ((((c) >> 1) & 3) << 3)

// ---------------------------------------------------------------------------
// K1 (MFMA): agg = tanh([nf|ef]@[Wn|We].T + bn + be); per-block row-sums ->
// part[cx][dblk][row]. BM=128, BN=64, BK=64, 512 thr, register prefetch.
// grid (8,16,2). (round-12 verbatim -- DO NOT PERTURB, round-11 lesson)
// ---------------------------------------------------------------------------
__global__ __launch_bounds__(512) void gnn_kernel(
    const float* __restrict__ lig_nf, const float* __restrict__ lig_ef,
    const float* __restrict__ rec_nf, const float* __restrict__ rec_ef,
    const float* __restrict__ Wn, const float* __restrict__ We,
    const float* __restrict__ bn, const float* __restrict__ be,
    float* __restrict__ part)   // [2][16][1024]
{
    __shared__ __attribute__((aligned(16))) short As[128 * 64];
    __shared__ __attribute__((aligned(16))) short Bs[64 * 64];
    __shared__ float red[128][2];

    const int t  = threadIdx.x;
    const int cx = blockIdx.z;
    const float* A0 = cx ? rec_nf : lig_nf;
    const float* A1 = cx ? rec_ef : lig_ef;
    const int j0 = blockIdx.x * 128;
    const int d0 = blockIdx.y * 64;

    const int wid  = t >> 6;
    const int wm   = wid >> 1;
    const int wn   = wid & 1;
    const int lane = t & 63;
    const int lr   = lane & 15;
    const int lg   = lane >> 4;

    f32x4 acc[2][2];
    #pragma unroll
    for (int m = 0; m < 2; ++m)
        #pragma unroll
        for (int n = 0; n < 2; ++n)
            acc[m][n] = (f32x4){0.f, 0.f, 0.f, 0.f};

    const int arow = t >> 2;
    const int akc  = (t & 3) * 16;
    const int brow = t >> 3;
    const int bkc  = (t & 7) * 8;

    float4 av[4], bv[2];
    {
        const float* ap = A0 + (size_t)(j0 + arow) * 1024 + akc;
        const float* bp = Wn + (size_t)(d0 + brow) * 1024 + bkc;
        #pragma unroll
        for (int q = 0; q < 4; ++q) av[q] = *reinterpret_cast<const float4*>(ap + q * 4);
        #pragma unroll
        for (int q = 0; q < 2; ++q) bv[q] = *reinterpret_cast<const float4*>(bp + q * 4);
    }

    for (int kb = 0; kb < 2048; kb += 64){
        __syncthreads();
        {
            const int ga = (t & 3) * 2;
            const int sa = arow & 7;
            *reinterpret_cast<half8*>(&As[arow * 64 + ((ga    ) ^ sa) * 8]) = pack2(av[0], av[1]);
            *reinterpret_cast<half8*>(&As[arow * 64 + ((ga + 1) ^ sa) * 8]) = pack2(av[2], av[3]);
            *reinterpret_cast<half8*>(&Bs[brow * 64 + (((t & 7)) ^ (brow & 7)) * 8]) = pack2(bv[0], bv[1]);
        }
        {
            const int kbn = (kb + 64) & 2047;
            const float* Asrc = (kbn < 1024) ? A0 : A1;
            const float* Bsrc = (kbn < 1024) ? Wn : We;
            const int kk = kbn & 1023;
            const float* ap = Asrc + (size_t)(j0 + arow) * 1024 + kk + akc;
            const float* bp = Bsrc + (size_t)(d0 + brow) * 1024 + kk + bkc;
            #pragma unroll
            for (int q = 0; q < 4; ++q) av[q] = *reinterpret_cast<const float4*>(ap + q * 4);
            #pragma unroll
            for (int q = 0; q < 2; ++q) bv[q] = *reinterpret_cast<const float4*>(bp + q * 4);
        }
        __syncthreads();

        #pragma unroll
        for (int ks = 0; ks < 2; ++ks){
            half8 Af[2], Bf[2];
            #pragma unroll
            for (int m = 0; m < 2; ++m){
                int row = wm * 32 + m * 16 + lr;
                int g   = ((ks * 4 + lg) ^ (row & 7)) * 8;
                Af[m] = *reinterpret_cast<const half8*>(&As[row * 64 + g]);
            }
            #pragma unroll
            for (int n = 0; n < 2; ++n){
                int col = wn * 32 + n * 16 + lr;
                int g   = ((ks * 4 + lg) ^ (col & 7)) * 8;
                Bf[n] = *reinterpret_cast<const half8*>(&Bs[col * 64 + g]);
            }
            #pragma unroll
            for (int m = 0; m < 2; ++m)
                #pragma unroll
                for (int n = 0; n < 2; ++n)
                    acc[m][n] = __builtin_amdgcn_mfma_f32_16x16x32_f16(
                        Af[m], Bf[n], acc[m][n], 0, 0, 0);
        }
    }

    float rowsum[2][4];
    #pragma unroll
    for (int m = 0; m < 2; ++m)
        #pragma unroll
        for (int jj = 0; jj < 4; ++jj) rowsum[m][jj] = 0.f;
    #pragma unroll
    for (int n = 0; n < 2; ++n){
        int d = d0 + wn * 32 + n * 16 + lr;
        float bias = bn[d] + be[d];
        #pragma unroll
        for (int m = 0; m < 2; ++m)
            #pragma unroll
            for (int jj = 0; jj < 4; ++jj)
                rowsum[m][jj] += tanh_fast(acc[m][n][jj] + bias);
    }
    #pragma unroll
    for (int mask = 1; mask < 16; mask <<= 1)
        #pragma unroll
        for (int m = 0; m < 2; ++m)
            #pragma unroll
            for (int jj = 0; jj < 4; ++jj)
                rowsum[m][jj] += __shfl_xor(rowsum[m][jj], mask);
    __syncthreads();
    if (lr == 0){
        #pragma unroll
        for (int m = 0; m < 2; ++m)
            #pragma unroll
            for (int jj = 0; jj < 4; ++jj)
                red[wm * 32 + m * 16 + lg * 4 + jj][wn] = rowsum[m][jj];
    }
    __syncthreads();
    if (t < 128)
        part[(size_t)cx * 16384 + (size_t)blockIdx.y * 1024 + j0 + t]
            = red[t][0] + red[t][1];
}

// ---------------------------------------------------------------------------
// K2: pp_kernel. grid 34 x 256 thr.
//  roles 0..31: P = nf@W.T via MFMA (80-row A-tile incl. +-8 halo margin,
//               coalesced staging), then U/V = 1D conv of P via second MFMA
//               (M=64 rows, N=32 co, K=96 = 3d x 32ci). Writes U16/V16.
//               cx = role>>4 (0: lig->U, 1: rec->V), r0 = (role&15)*64.
//  role 32    : cveck -> Kp (round-12 verbatim)
//  role 33    : w2pack -> w2f16 (round-12 verbatim)
// ---------------------------------------------------------------------------
__global__ __launch_bounds__(256) void pp_kernel(
    const float* __restrict__ lig_nf, const float* __restrict__ rec_nf,
    const float* __restrict__ W_hopi, const float* __restrict__ b_hopi,
    const float* __restrict__ w1, const float* __restrict__ b1,
    const float* __restrict__ w2,
    const float* __restrict__ part,
    float* __restrict__ Kp, short* __restrict__ U16, short* __restrict__ V16,
    short* __restrict__ w2f16)
{
    __shared__ __attribute__((aligned(16))) char smem[46208];
    const int t = threadIdx.x;
    const int role = blockIdx.x;

    if (role < 32){
        // LDS layout: As 80x64 h (10240 B) @0 ; Bs 32x64 h (4096 B) @10240 ;
        // Pz 80 rows stride 40 h (6400 B) @14336 ; Ws 3x32 stride 104 h
        // (19968 B) @20736. Total 40704 B.
        short* As = reinterpret_cast<short*>(smem);
        short* Bs = reinterpret_cast<short*>(smem + 10240);
        short* Pz = reinterpret_cast<short*>(smem + 14336);
        short* Ws = reinterpret_cast<short*>(smem + 20736);

        const int cx = role >> 4;
        const int r0 = (role & 15) * 64;
        const float* nf = cx ? rec_nf : lig_nf;
        const float* W  = W_hopi + (cx ? 1024 : 0);
        short* O = cx ? V16 : U16;

        const int wid = t >> 6;
        const int lane = t & 63;
        const int lr = lane & 15;
        const int lg = lane >> 4;

        // ---- stage Ws[cs][co][k=d*32+ci] (stride 104): tap-subset sums ----
        for (int e = t; e < 9216; e += 256){
            int cs  = e / 3072;
            int rem = e - cs * 3072;
            int co  = rem / 96;
            int k   = rem - co * 96;
            int d   = k >> 5;
            int ci  = k & 31;
            int o_lo = (cs == 1) ? 1 : 0;
            int o_hi = (cs == 2) ? 1 : 2;
            float s = 0.f;
            for (int o = o_lo; o <= o_hi; ++o){
                int tap = cx ? (o * 3 + d) : (d * 3 + o);
                s += w1[co * 288 + ci * 9 + tap];
            }
            Ws[(cs * 32 + co) * 104 + k] = f2h_bits(s);
        }

        // ---- P GEMM: rows r0-8 .. r0+71 (80), cols 32 h, K=1024 ----
        f32x4 acc[2][2];
        #pragma unroll
        for (int mi = 0; mi < 2; ++mi)
            #pragma unroll
            for (int n = 0; n < 2; ++n)
                acc[mi][n] = (f32x4){0.f, 0.f, 0.f, 0.f};

        for (int kb = 0; kb < 16; ++kb){
            const int kcol = kb * 64;
            __syncthreads();
            // stage A: 80 rows x 64 k (coalesced float4, zero out-of-range)
            for (int e = t; e < 320; e += 256){
                int rowl = e >> 2;
                int grow = r0 - 8 + rowl;
                int chunk = (e & 3) * 16;
                float4 a0, a1, a2, a3;
                if ((unsigned)grow < 1024u){
                    const float* ap = nf + (size_t)grow * 1024 + kcol + chunk;
                    a0 = *reinterpret_cast<const float4*>(ap);
                    a1 = *reinterpret_cast<const float4*>(ap + 4);
                    a2 = *reinterpret_cast<const float4*>(ap + 8);
                    a3 = *reinterpret_cast<const float4*>(ap + 12);
                } else {
                    a0 = a1 = a2 = a3 = make_float4(0.f, 0.f, 0.f, 0.f);
                }
                int ga = (e & 3) * 2;
                int sa = rowl & 7;
                *reinterpret_cast<half8*>(&As[rowl * 64 + ((ga    ) ^ sa) * 8]) = pack2(a0, a1);
                *reinterpret_cast<half8*>(&As[rowl * 64 + ((ga + 1) ^ sa) * 8]) = pack2(a2, a3);
            }
            // stage B: 32 h rows x 64 k (coalesced)
            {
                int row = t >> 3;
                int kc  = (t & 7) * 8;
                const float* bp = W + (size_t)row * 2048 + kcol + kc;
                float4 b0 = *reinterpret_cast<const float4*>(bp);
                float4 b1 = *reinterpret_cast<const float4*>(bp + 4);
                *reinterpret_cast<half8*>(&Bs[row * 64 + ((t & 7) ^ (row & 7)) * 8]) = pack2(b0, b1);
            }
            __syncthreads();
            #pragma unroll
            for (int mi = 0; mi < 2; ++mi){
                int mf = wid + mi * 4;
                if (mf >= 5) break;                 // wave-uniform
                #pragma unroll
                for (int ks = 0; ks < 2; ++ks){
                    int ar = mf * 16 + lr;
                    half8 Af = *reinterpret_cast<const half8*>(
                        &As[ar * 64 + ((ks * 4 + lg) ^ (ar & 7)) * 8]);
                    #pragma unroll
                    for (int n = 0; n < 2; ++n){
                        int col = n * 16 + lr;
                        half8 Bf = *reinterpret_cast<const half8*>(
                            &Bs[col * 64 + ((ks * 4 + lg) ^ (col & 7)) * 8]);
                        acc[mi][n] = __builtin_amdgcn_mfma_f32_16x16x32_f16(
                            Af, Bf, acc[mi][n], 0, 0, 0);
                    }
                }
            }
        }
        // ---- write P (f16) to Pz (stride 40) ----
        #pragma unroll
        for (int mi = 0; mi < 2; ++mi){
            int mf = wid + mi * 4;
            if (mf >= 5) break;
            #pragma unroll
            for (int n = 0; n < 2; ++n)
                #pragma unroll
                for (int jj = 0; jj < 4; ++jj){
                    int rowl = mf * 16 + lg * 4 + jj;
                    Pz[rowl * 40 + n * 16 + lr] = f2h_bits(acc[mi][n][jj]);
                }
        }
        __syncthreads();

        // ---- uv GEMM: U[r][co] = sum_{d,ci} P[r+d-1][ci] * Ws[cs][co][k] ----
        f32x4 uacc[3][2];
        #pragma unroll
        for (int cs = 0; cs < 3; ++cs)
            #pragma unroll
            for (int n = 0; n < 2; ++n)
                uacc[cs][n] = (f32x4){0.f, 0.f, 0.f, 0.f};
        #pragma unroll
        for (int d = 0; d < 3; ++d){
            int ar = wid * 16 + lr;                 // local output row
            half8 Ap = *reinterpret_cast<const half8*>(
                &Pz[(7 + ar + d) * 40 + lg * 8]);
            #pragma unroll
            for (int cs = 0; cs < 3; ++cs)
                #pragma unroll
                for (int n = 0; n < 2; ++n){
                    half8 Bp = *reinterpret_cast<const half8*>(
                        &Ws[(cs * 32 + n * 16 + lr) * 104 + d * 32 + lg * 8]);
                    uacc[cs][n] = __builtin_amdgcn_mfma_f32_16x16x32_f16(
                        Ap, Bp, uacc[cs][n], 0, 0, 0);
                }
        }
        #pragma unroll
        for (int cs = 0; cs < 3; ++cs)
            #pragma unroll
            for (int n = 0; n < 2; ++n)
                #pragma unroll
                for (int jj = 0; jj < 4; ++jj){
                    int grow = r0 + wid * 16 + lg * 4 + jj;
                    O[((size_t)(cs << 10) + grow) * 32 + n * 16 + lr]
                        = f2h_bits(uacc[cs][n][jj]);
                }
        return;
    }

    if (role == 33){
        // ---------------- w2pack role ----------------
        for (int e = t; e < 9216; e += 256){
            int co  = e / 288;
            int rem = e - co * 288;
            int ci  = rem / 9;
            int tap = rem - ci * 9;
            w2f16[(tap * 32 + co) * 32 + (ci ^ SWZ(co))] = f2h_bits(w2[e]);
        }
        return;
    }

    // ---------------- cveck role (round-12 verbatim) ----------------
    float* ws_l = reinterpret_cast<float*>(smem);
    float* ws_r = reinterpret_cast<float*>(smem + 4096);
    float* red  = reinterpret_cast<float*>(smem + 8192);
    float* cvs  = reinterpret_cast<float*>(smem + 9216);
    float* w1s  = reinterpret_cast<float*>(smem + 9344);

    #pragma unroll
    for (int q = 0; q < 9; ++q){
        int idx = (t + q * 256) * 4;
        *reinterpret_cast<float4*>(&w1s[idx]) =
            *reinterpret_cast<const float4*>(w1 + idx);
    }
    for (int j = t; j < 1024; j += 256){
        float sl = 0.f, sr = 0.f;
        #pragma unroll
        for (int b = 0; b < 16; ++b){
            sl += part[b * 1024 + j];
            sr += part[16384 + b * 1024 + j];
        }
        ws_l[j] = sl; ws_r[j] = sr;
    }
    __syncthreads();
    {
        const int h = t & 31;
        const int seg = t >> 5;
        const float* wl = W_hopi + (size_t)h * 2048 + seg * 128;
        const float* wr = wl + 1024;
        float s = 0.f;
        #pragma unroll 8
        for (int j = 0; j < 128; j += 4){
            float4 a = *reinterpret_cast<const float4*>(wl + j);
            float4 b = *reinterpret_cast<const float4*>(wr + j);
            const float* l = &ws_l[seg * 128 + j];
            const float* r = &ws_r[seg * 128 + j];
            s = fmaf(l[0], a.x, s); s = fmaf(l[1], a.y, s);
            s = fmaf(l[2], a.z, s); s = fmaf(l[3], a.w, s);
            s = fmaf(r[0], b.x, s); s = fmaf(r[1], b.y, s);
            s = fmaf(r[2], b.z, s); s = fmaf(r[3], b.w, s);
        }
        red[t] = s;
    }
    __syncthreads();
    if (t < 32){
        float tot = b_hopi[t];
        #pragma unroll
        for (int g = 0; g < 8; ++g) tot += red[g * 32 + t];
        cvs[t] = tot;
    }
    __syncthreads();
    for (int e = t; e < 288; e += 256){
        int co  = e & 31;
        int cse = e >> 5;
        int yc  = cse / 3, xc = cse - yc * 3;
        float sum = b1[co];
        for (int ci = 0; ci < 32; ++ci){
            const float* wp = &w1s[co * 288 + ci * 9];
            float t00 = wp[0], t01 = wp[1], t02 = wp[2];
            float t10 = wp[3], t11 = wp[4], t12 = wp[5];
            float t20 = wp[6], t21 = wp[7], t22 = wp[8];
            float r0, r1, r2;
            if (xc == 0){ r0 = t00+t01+t02; r1 = t10+t11+t12; r2 = t20+t21+t22; }
            else if (xc == 1){ r0 = t01+t02; r1 = t11+t12; r2 = t21+t22; }
            else { r0 = t00+t01; r1 = t10+t11; r2 = t20+t21; }
            float wsum = (yc == 0) ? (r0+r1+r2) : ((yc == 1) ? (r1+r2) : (r0+r1));
            sum = fmaf(cvs[ci], wsum, sum);
        }
        Kp[cse * 32 + co] = sum;
    }
}

// ---------------------------------------------------------------------------
// K3: stage ys = relu(U+V+K'), wB by uint4 copy of prepacked w2f16, then
// conv2+relu+conv3 on f16 MFMA. LDS = 39,168 B. block 512, grid 64x64.
// (round-12 verbatim)
// ---------------------------------------------------------------------------
__global__ __launch_bounds__(512) void conv_kernel(
    const short* __restrict__ U16, const short* __restrict__ V16,
    const float* __restrict__ Kp, const short* __restrict__ w2f16,
    const float* __restrict__ b2,
    const float* __restrict__ w3, const float* __restrict__ b3,
    float* __restrict__ outp)
{
    __shared__ __attribute__((aligned(16))) short ys[18 * 18 * 32];
    __shared__ __attribute__((aligned(16))) short wB[9 * 32 * 32];

    const int t    = threadIdx.x;
    const int oy0  = blockIdx.y * 16;
    const int ox0  = blockIdx.x * 16;
    const int wid  = t >> 6;
    const int lane = t & 63;
    const int lr   = lane & 15;
    const int lg   = lane >> 4;

    {
        const uint4* src = reinterpret_cast<const uint4*>(w2f16);
        uint4* dst = reinterpret_cast<uint4*>(wB);
        #pragma unroll
        for (int e = t; e < 1152; e += 512)
            dst[e] = src[e];
    }
    #pragma unroll
    for (int pass = 0; pass < 6; ++pass){
        int idx = t + pass * 512;
        if (idx < 2592){
            int po  = idx >> 3;
            int cp  = (idx & 7) * 4;
            int ryo = po / 18;
            int rxo = po - ryo * 18;
            int gy = oy0 - 1 + ryo, gx = ox0 - 1 + rxo;
            half4 h = {(_Float16)0.f, (_Float16)0.f, (_Float16)0.f, (_Float16)0.f};
            if ((unsigned)gy < 1024u && (unsigned)gx < 1024u){
                int yc = (gy == 0) ? 1 : ((gy == 1023) ? 2 : 0);
                int xc = (gx == 0) ? 1 : ((gx == 1023) ? 2 : 0);
                half4 u = *reinterpret_cast<const half4*>(
                    &U16[((size_t)(xc << 10) + gy) * 32 + cp]);
                half4 v = *reinterpret_cast<const half4*>(
                    &V16[((size_t)(yc << 10) + gx) * 32 + cp]);
                float4 k = *reinterpret_cast<const float4*>(&Kp[(yc * 3 + xc) * 32 + cp]);
                h[0] = (_Float16)fmaxf((float)u[0] + (float)v[0] + k.x, 0.f);
                h[1] = (_Float16)fmaxf((float)u[1] + (float)v[1] + k.y, 0.f);
                h[2] = (_Float16)fmaxf((float)u[2] + (float)v[2] + k.z, 0.f);
                h[3] = (_Float16)fmaxf((float)u[3] + (float)v[3] + k.w, 0.f);
            }
            *reinterpret_cast<half4*>(&ys[po * 32 + (cp ^ SWZ(rxo))]) = h;
        }
    }
    __syncthreads();

    {
        half8 Bf[2][9];
        float bias[2], w3v[2];
        #pragma unroll
        for (int n = 0; n < 2; ++n){
            int co = n * 16 + lr;
            bias[n] = b2[co];
            w3v[n]  = w3[co];
            #pragma unroll
            for (int tap = 0; tap < 9; ++tap)
                Bf[n][tap] = *reinterpret_cast<const half8*>(
                    &wB[(tap * 32 + co) * 32 + ((lg * 8) ^ SWZ(co))]);
        }
        const float b3v = b3[0];
        for (int s = wid; s < 16; s += 8){
            int p  = s * 16 + lr;
            int ry = p >> 4;
            int rx = p & 15;
            f32x4 acc0 = {0.f, 0.f, 0.f, 0.f};
            f32x4 acc1 = {0.f, 0.f, 0.f, 0.f};
            #pragma unroll
            for (int tap = 0; tap < 9; ++tap){
                const int dy = tap / 3, dx = tap - (tap / 3) * 3;
                int pix = (ry + dy) * 18 + rx + dx;
                half8 A = *reinterpret_cast<const half8*>(
                    &ys[pix * 32 + ((lg * 8) ^ SWZ(rx + dx))]);
                acc0 = __builtin_amdgcn_mfma_f32_16x16x32_f16(A, Bf[0][tap], acc0, 0, 0, 0);
                acc1 = __builtin_amdgcn_mfma_f32_16x16x32_f16(A, Bf[1][tap], acc1, 0, 0, 0);
            }
            float part[4];
            #pragma unroll
            for (int j = 0; j < 4; ++j)
                part[j] = w3v[0] * fmaxf(acc0[j] + bias[0], 0.f)
                        + w3v[1] * fmaxf(acc1[j] + bias[1], 0.f);
            #pragma unroll
            for (int m = 1; m < 16; m <<= 1)
                #pragma unroll
                for (int j = 0; j < 4; ++j)
                    part[j] += __shfl_xor(part[j], m);
            if (lr == 0){
                float4 o = make_float4(part[0] + b3v, part[1] + b3v,
                                       part[2] + b3v, part[3] + b3v);
                *reinterpret_cast<float4*>(outp + (size_t)(oy0 + s) * 1024 + ox0 + lg * 4) = o;
            }
        }
    }
}

// ---------------------------------------------------------------------------
extern "C" void kernel_launch(void* const* d_in, const int* in_sizes, int n_in,
                              void* d_out, int out_size, void* d_ws, size_t ws_size,
                              hipStream_t stream)
{
    const float* lig_nf = (const float*)d_in[0];
    const float* lig_ef = (const float*)d_in[1];
    const float* rec_nf = (const float*)d_in[3];
    const float* rec_ef = (const float*)d_in[4];
    const float* Wn     = (const float*)d_in[6];
    const float* bn     = (const float*)d_in[7];
    const float* We     = (const float*)d_in[8];
    const float* be     = (const float*)d_in[9];
    const float* W_hopi = (const float*)d_in[12];
    const float* b_hopi = (const float*)d_in[13];
    const float* w1     = (const float*)d_in[14];
    const float* b1     = (const float*)d_in[15];
    const float* w2     = (const float*)d_in[16];
    const float* b2     = (const float*)d_in[17];
    const float* w3     = (const float*)d_in[18];
    const float* b3     = (const float*)d_in[19];
    float* outp = (float*)d_out;

    float* part  = (float*)d_ws;                              // [2][16][1024] f32
    float* Kp    = (float*)((char*)d_ws + 393216);            // 3*3*32 f32
    short* U16   = (short*)((char*)d_ws + 394368);            // 3*1024*32 f16
    short* V16   = (short*)((char*)d_ws + 590976);            // 3*1024*32 f16
    short* w2f16 = (short*)((char*)d_ws + 787584);            // 9216 f16 swizzled

    dim3 g1(8, 16, 2);
    gnn_kernel<<<g1, 512, 0, stream>>>(lig_nf, lig_ef, rec_nf, rec_ef,
                                       Wn, We, bn, be, part);
    pp_kernel<<<34, 256, 0, stream>>>(lig_nf, rec_nf, W_hopi, b_hopi,
                                      w1, b1, w2, part, Kp, U16, V16, w2f16);
    dim3 g3(64, 64);
    conv_kernel<<<g3, 512, 0, stream>>>(U16, V16, Kp, w2f16, b2, w3, b3, outp);
}

// Round 15
// 117.918 us; speedup vs baseline: 1.3935x; 1.0521x over previous
//
#include <hip/hip_runtime.h>

// All tensors float32. Math structure exploited:
//  - softmax over axis of size 1 == 1.0 -> attn all-ones, Wa/ba dead.
//  - weighted = row-sum of tanh(agg), broadcast over COLUMNS (N==D quirk).
//  - lig_p = nf@Wl.T + const  ->  x0[h,i,j] = PL[i,h] + PR[j,h] + c[h]
//  - conv1 is LINEAR in rank-structured x0: y1_pre = U[xc][y] + V[yc][x] + K'.
//    conv stages ys = relu(U+V+K'); conv2+conv3 on f16 MFMA.
//  - ROUND-15: (a) conv interior fast path (93.8% of blocks have no border
//    pixel: case always (0,0)) with packed-f16 staging (v_pk_add/max_f16,
//    no f32 round-trip); (b) gnn depth-2 register prefetch (loads issued two
//    phases ahead; slab period ~200cyc only partially covered at depth 1).

typedef _Float16 half8 __attribute__((ext_vector_type(8)));
typedef _Float16 half4 __attribute__((ext_vector_type(4)));
typedef float    f32x4 __attribute__((ext_vector_type(4)));

__device__ __forceinline__ short f2h_bits(float f){
    _Float16 h = (_Float16)f;          // RNE
    return __builtin_bit_cast(short, h);
}
__device__ __forceinline__ half8 pack2(const float4& x, const float4& y){
    half8 r;
    r[0] = (_Float16)x.x; r[1] = (_Float16)x.y;
    r[2] = (_Float16)x.z; r[3] = (_Float16)x.w;
    r[4] = (_Float16)y.x; r[5] = (_Float16)y.y;
    r[6] = (_Float16)y.z; r[7] = (_Float16)y.w;
    return r;
}
__device__ __forceinline__ float tanh_fast(float x){
    float e = __expf(2.f * x);
    return 1.f - 2.f / (e + 1.f);
}

// ci-block swizzle for conv LDS tiles (round-4 verified layout)
#define SWZ(c) ((((c) >> 1) & 3) << 3)

// ---------------------------------------------------------------------------
// K1 (MFMA): agg = tanh([nf|ef]@[Wn|We].T + bn + be); per-block row-sums ->
// part[cx][dblk][row]. BM=128, BN=64, BK=64, 512 thr, DEPTH-2 reg prefetch.
// grid (8,16,2).
// ---------------------------------------------------------------------------
#define GNN_LOAD(AV, BV, KBN) {                                              \
    const int kbn_ = (KBN) & 2047;                                           \
    const float* Asrc_ = (kbn_ < 1024) ? A0 : A1;                            \
    const float* Bsrc_ = (kbn_ < 1024) ? Wn : We;                            \
    const int kk_ = kbn_ & 1023;                                             \
    const float* ap_ = Asrc_ + (size_t)(j0 + arow) * 1024 + kk_ + akc;       \
    const float* bp_ = Bsrc_ + (size_t)(d0 + brow) * 1024 + kk_ + bkc;       \
    AV[0] = *reinterpret_cast<const float4*>(ap_);                           \
    AV[1] = *reinterpret_cast<const float4*>(ap_ + 4);                       \
    AV[2] = *reinterpret_cast<const float4*>(ap_ + 8);                       \
    AV[3] = *reinterpret_cast<const float4*>(ap_ + 12);                      \
    BV[0] = *reinterpret_cast<const float4*>(bp_);                           \
    BV[1] = *reinterpret_cast<const float4*>(bp_ + 4);                       \
}

#define GNN_STAGE(AV, BV) {                                                  \
    const int ga_ = (t & 3) * 2;                                             \
    const int sa_ = arow & 7;                                                \
    *reinterpret_cast<half8*>(&As[arow * 64 + ((ga_    ) ^ sa_) * 8]) = pack2(AV[0], AV[1]); \
    *reinterpret_cast<half8*>(&As[arow * 64 + ((ga_ + 1) ^ sa_) * 8]) = pack2(AV[2], AV[3]); \
    *reinterpret_cast<half8*>(&Bs[brow * 64 + ((t & 7) ^ (brow & 7)) * 8]) = pack2(BV[0], BV[1]); \
}

#define GNN_MFMA() {                                                         \
    _Pragma("unroll")                                                        \
    for (int ks = 0; ks < 2; ++ks){                                          \
        half8 Af[2], Bf[2];                                                  \
        _Pragma("unroll")                                                    \
        for (int m = 0; m < 2; ++m){                                         \
            int row = wm * 32 + m * 16 + lr;                                 \
            int g   = ((ks * 4 + lg) ^ (row & 7)) * 8;                       \
            Af[m] = *reinterpret_cast<const half8*>(&As[row * 64 + g]);      \
        }                                                                    \
        _Pragma("unroll")                                                    \
        for (int n = 0; n < 2; ++n){                                         \
            int col = wn * 32 + n * 16 + lr;                                 \
            int g   = ((ks * 4 + lg) ^ (col & 7)) * 8;                       \
            Bf[n] = *reinterpret_cast<const half8*>(&Bs[col * 64 + g]);      \
        }                                                                    \
        _Pragma("unroll")                                                    \
        for (int m = 0; m < 2; ++m)                                          \
            _Pragma("unroll")                                                \
            for (int n = 0; n < 2; ++n)                                      \
                acc[m][n] = __builtin_amdgcn_mfma_f32_16x16x32_f16(          \
                    Af[m], Bf[n], acc[m][n], 0, 0, 0);                       \
    }                                                                        \
}

__global__ __launch_bounds__(512) void gnn_kernel(
    const float* __restrict__ lig_nf, const float* __restrict__ lig_ef,
    const float* __restrict__ rec_nf, const float* __restrict__ rec_ef,
    const float* __restrict__ Wn, const float* __restrict__ We,
    const float* __restrict__ bn, const float* __restrict__ be,
    float* __restrict__ part)   // [2][16][1024]
{
    __shared__ __attribute__((aligned(16))) short As[128 * 64];
    __shared__ __attribute__((aligned(16))) short Bs[64 * 64];
    __shared__ float red[128][2];

    const int t  = threadIdx.x;
    const int cx = blockIdx.z;
    const float* A0 = cx ? rec_nf : lig_nf;
    const float* A1 = cx ? rec_ef : lig_ef;
    const int j0 = blockIdx.x * 128;
    const int d0 = blockIdx.y * 64;

    const int wid  = t >> 6;
    const int wm   = wid >> 1;
    const int wn   = wid & 1;
    const int lane = t & 63;
    const int lr   = lane & 15;
    const int lg   = lane >> 4;

    f32x4 acc[2][2];
    #pragma unroll
    for (int m = 0; m < 2; ++m)
        #pragma unroll
        for (int n = 0; n < 2; ++n)
            acc[m][n] = (f32x4){0.f, 0.f, 0.f, 0.f};

    const int arow = t >> 2;
    const int akc  = (t & 3) * 16;
    const int brow = t >> 3;
    const int bkc  = (t & 7) * 8;

    float4 avA[4], bvA[2], avB[4], bvB[2];
    GNN_LOAD(avA, bvA, 0);
    GNN_LOAD(avB, bvB, 64);

    for (int kb = 0; kb < 2048; kb += 128){
        __syncthreads();               // prior MFMA's LDS reads done
        GNN_STAGE(avA, bvA);
        GNN_LOAD(avA, bvA, kb + 128);  // two phases ahead
        __syncthreads();
        GNN_MFMA();
        __syncthreads();
        GNN_STAGE(avB, bvB);
        GNN_LOAD(avB, bvB, kb + 192);
        __syncthreads();
        GNN_MFMA();
    }

    float rowsum[2][4];
    #pragma unroll
    for (int m = 0; m < 2; ++m)
        #pragma unroll
        for (int jj = 0; jj < 4; ++jj) rowsum[m][jj] = 0.f;
    #pragma unroll
    for (int n = 0; n < 2; ++n){
        int d = d0 + wn * 32 + n * 16 + lr;
        float bias = bn[d] + be[d];
        #pragma unroll
        for (int m = 0; m < 2; ++m)
            #pragma unroll
            for (int jj = 0; jj < 4; ++jj)
                rowsum[m][jj] += tanh_fast(acc[m][n][jj] + bias);
    }
    #pragma unroll
    for (int mask = 1; mask < 16; mask <<= 1)
        #pragma unroll
        for (int m = 0; m < 2; ++m)
            #pragma unroll
            for (int jj = 0; jj < 4; ++jj)
                rowsum[m][jj] += __shfl_xor(rowsum[m][jj], mask);
    __syncthreads();
    if (lr == 0){
        #pragma unroll
        for (int m = 0; m < 2; ++m)
            #pragma unroll
            for (int jj = 0; jj < 4; ++jj)
                red[wm * 32 + m * 16 + lg * 4 + jj][wn] = rowsum[m][jj];
    }
    __syncthreads();
    if (t < 128)
        part[(size_t)cx * 16384 + (size_t)blockIdx.y * 1024 + j0 + t]
            = red[t][0] + red[t][1];
}

// ---------------------------------------------------------------------------
// K2: pp_kernel. grid 34 x 256 thr. (round-14 verbatim)
//  roles 0..31: P via MFMA GEMM (80-row tile incl. halo), uv via second MFMA.
//  role 32: cveck -> Kp ; role 33: w2pack -> w2f16
// ---------------------------------------------------------------------------
__global__ __launch_bounds__(256) void pp_kernel(
    const float* __restrict__ lig_nf, const float* __restrict__ rec_nf,
    const float* __restrict__ W_hopi, const float* __restrict__ b_hopi,
    const float* __restrict__ w1, const float* __restrict__ b1,
    const float* __restrict__ w2,
    const float* __restrict__ part,
    float* __restrict__ Kp, short* __restrict__ U16, short* __restrict__ V16,
    short* __restrict__ w2f16)
{
    __shared__ __attribute__((aligned(16))) char smem[46208];
    const int t = threadIdx.x;
    const int role = blockIdx.x;

    if (role < 32){
        short* As = reinterpret_cast<short*>(smem);
        short* Bs = reinterpret_cast<short*>(smem + 10240);
        short* Pz = reinterpret_cast<short*>(smem + 14336);
        short* Ws = reinterpret_cast<short*>(smem + 20736);

        const int cx = role >> 4;
        const int r0 = (role & 15) * 64;
        const float* nf = cx ? rec_nf : lig_nf;
        const float* W  = W_hopi + (cx ? 1024 : 0);
        short* O = cx ? V16 : U16;

        const int wid = t >> 6;
        const int lane = t & 63;
        const int lr = lane & 15;
        const int lg = lane >> 4;

        for (int e = t; e < 9216; e += 256){
            int cs  = e / 3072;
            int rem = e - cs * 3072;
            int co  = rem / 96;
            int k   = rem - co * 96;
            int d   = k >> 5;
            int ci  = k & 31;
            int o_lo = (cs == 1) ? 1 : 0;
            int o_hi = (cs == 2) ? 1 : 2;
            float s = 0.f;
            for (int o = o_lo; o <= o_hi; ++o){
                int tap = cx ? (o * 3 + d) : (d * 3 + o);
                s += w1[co * 288 + ci * 9 + tap];
            }
            Ws[(cs * 32 + co) * 104 + k] = f2h_bits(s);
        }

        f32x4 acc[2][2];
        #pragma unroll
        for (int mi = 0; mi < 2; ++mi)
            #pragma unroll
            for (int n = 0; n < 2; ++n)
                acc[mi][n] = (f32x4){0.f, 0.f, 0.f, 0.f};

        for (int kb = 0; kb < 16; ++kb){
            const int kcol = kb * 64;
            __syncthreads();
            for (int e = t; e < 320; e += 256){
                int rowl = e >> 2;
                int grow = r0 - 8 + rowl;
                int chunk = (e & 3) * 16;
                float4 a0, a1, a2, a3;
                if ((unsigned)grow < 1024u){
                    const float* ap = nf + (size_t)grow * 1024 + kcol + chunk;
                    a0 = *reinterpret_cast<const float4*>(ap);
                    a1 = *reinterpret_cast<const float4*>(ap + 4);
                    a2 = *reinterpret_cast<const float4*>(ap + 8);
                    a3 = *reinterpret_cast<const float4*>(ap + 12);
                } else {
                    a0 = a1 = a2 = a3 = make_float4(0.f, 0.f, 0.f, 0.f);
                }
                int ga = (e & 3) * 2;
                int sa = rowl & 7;
                *reinterpret_cast<half8*>(&As[rowl * 64 + ((ga    ) ^ sa) * 8]) = pack2(a0, a1);
                *reinterpret_cast<half8*>(&As[rowl * 64 + ((ga + 1) ^ sa) * 8]) = pack2(a2, a3);
            }
            {
                int row = t >> 3;
                int kc  = (t & 7) * 8;
                const float* bp = W + (size_t)row * 2048 + kcol + kc;
                float4 b0 = *reinterpret_cast<const float4*>(bp);
                float4 b1 = *reinterpret_cast<const float4*>(bp + 4);
                *reinterpret_cast<half8*>(&Bs[row * 64 + ((t & 7) ^ (row & 7)) * 8]) = pack2(b0, b1);
            }
            __syncthreads();
            #pragma unroll
            for (int mi = 0; mi < 2; ++mi){
                int mf = wid + mi * 4;
                if (mf >= 5) break;
                #pragma unroll
                for (int ks = 0; ks < 2; ++ks){
                    int ar = mf * 16 + lr;
                    half8 Af = *reinterpret_cast<const half8*>(
                        &As[ar * 64 + ((ks * 4 + lg) ^ (ar & 7)) * 8]);
                    #pragma unroll
                    for (int n = 0; n < 2; ++n){
                        int col = n * 16 + lr;
                        half8 Bf = *reinterpret_cast<const half8*>(
                            &Bs[col * 64 + ((ks * 4 + lg) ^ (col & 7)) * 8]);
                        acc[mi][n] = __builtin_amdgcn_mfma_f32_16x16x32_f16(
                            Af, Bf, acc[mi][n], 0, 0, 0);
                    }
                }
            }
        }
        #pragma unroll
        for (int mi = 0; mi < 2; ++mi){
            int mf = wid + mi * 4;
            if (mf >= 5) break;
            #pragma unroll
            for (int n = 0; n < 2; ++n)
                #pragma unroll
                for (int jj = 0; jj < 4; ++jj){
                    int rowl = mf * 16 + lg * 4 + jj;
                    Pz[rowl * 40 + n * 16 + lr] = f2h_bits(acc[mi][n][jj]);
                }
        }
        __syncthreads();

        f32x4 uacc[3][2];
        #pragma unroll
        for (int cs = 0; cs < 3; ++cs)
            #pragma unroll
            for (int n = 0; n < 2; ++n)
                uacc[cs][n] = (f32x4){0.f, 0.f, 0.f, 0.f};
        #pragma unroll
        for (int d = 0; d < 3; ++d){
            int ar = wid * 16 + lr;
            half8 Ap = *reinterpret_cast<const half8*>(
                &Pz[(7 + ar + d) * 40 + lg * 8]);
            #pragma unroll
            for (int cs = 0; cs < 3; ++cs)
                #pragma unroll
                for (int n = 0; n < 2; ++n){
                    half8 Bp = *reinterpret_cast<const half8*>(
                        &Ws[(cs * 32 + n * 16 + lr) * 104 + d * 32 + lg * 8]);
                    uacc[cs][n] = __builtin_amdgcn_mfma_f32_16x16x32_f16(
                        Ap, Bp, uacc[cs][n], 0, 0, 0);
                }
        }
        #pragma unroll
        for (int cs = 0; cs < 3; ++cs)
            #pragma unroll
            for (int n = 0; n < 2; ++n)
                #pragma unroll
                for (int jj = 0; jj < 4; ++jj){
                    int grow = r0 + wid * 16 + lg * 4 + jj;
                    O[((size_t)(cs << 10) + grow) * 32 + n * 16 + lr]
                        = f2h_bits(uacc[cs][n][jj]);
                }
        return;
    }

    if (role == 33){
        for (int e = t; e < 9216; e += 256){
            int co  = e / 288;
            int rem = e - co * 288;
            int ci  = rem / 9;
            int tap = rem - ci * 9;
            w2f16[(tap * 32 + co) * 32 + (ci ^ SWZ(co))] = f2h_bits(w2[e]);
        }
        return;
    }

    // cveck role
    float* ws_l = reinterpret_cast<float*>(smem);
    float* ws_r = reinterpret_cast<float*>(smem + 4096);
    float* red  = reinterpret_cast<float*>(smem + 8192);
    float* cvs  = reinterpret_cast<float*>(smem + 9216);
    float* w1s  = reinterpret_cast<float*>(smem + 9344);

    #pragma unroll
    for (int q = 0; q < 9; ++q){
        int idx = (t + q * 256) * 4;
        *reinterpret_cast<float4*>(&w1s[idx]) =
            *reinterpret_cast<const float4*>(w1 + idx);
    }
    for (int j = t; j < 1024; j += 256){
        float sl = 0.f, sr = 0.f;
        #pragma unroll
        for (int b = 0; b < 16; ++b){
            sl += part[b * 1024 + j];
            sr += part[16384 + b * 1024 + j];
        }
        ws_l[j] = sl; ws_r[j] = sr;
    }
    __syncthreads();
    {
        const int h = t & 31;
        const int seg = t >> 5;
        const float* wl = W_hopi + (size_t)h * 2048 + seg * 128;
        const float* wr = wl + 1024;
        float s = 0.f;
        #pragma unroll 8
        for (int j = 0; j < 128; j += 4){
            float4 a = *reinterpret_cast<const float4*>(wl + j);
            float4 b = *reinterpret_cast<const float4*>(wr + j);
            const float* l = &ws_l[seg * 128 + j];
            const float* r = &ws_r[seg * 128 + j];
            s = fmaf(l[0], a.x, s); s = fmaf(l[1], a.y, s);
            s = fmaf(l[2], a.z, s); s = fmaf(l[3], a.w, s);
            s = fmaf(r[0], b.x, s); s = fmaf(r[1], b.y, s);
            s = fmaf(r[2], b.z, s); s = fmaf(r[3], b.w, s);
        }
        red[t] = s;
    }
    __syncthreads();
    if (t < 32){
        float tot = b_hopi[t];
        #pragma unroll
        for (int g = 0; g < 8; ++g) tot += red[g * 32 + t];
        cvs[t] = tot;
    }
    __syncthreads();
    for (int e = t; e < 288; e += 256){
        int co  = e & 31;
        int cse = e >> 5;
        int yc  = cse / 3, xc = cse - yc * 3;
        float sum = b1[co];
        for (int ci = 0; ci < 32; ++ci){
            const float* wp = &w1s[co * 288 + ci * 9];
            float t00 = wp[0], t01 = wp[1], t02 = wp[2];
            float t10 = wp[3], t11 = wp[4], t12 = wp[5];
            float t20 = wp[6], t21 = wp[7], t22 = wp[8];
            float r0, r1, r2;
            if (xc == 0){ r0 = t00+t01+t02; r1 = t10+t11+t12; r2 = t20+t21+t22; }
            else if (xc == 1){ r0 = t01+t02; r1 = t11+t12; r2 = t21+t22; }
            else { r0 = t00+t01; r1 = t10+t11; r2 = t20+t21; }
            float wsum = (yc == 0) ? (r0+r1+r2) : ((yc == 1) ? (r1+r2) : (r0+r1));
            sum = fmaf(cvs[ci], wsum, sum);
        }
        Kp[cse * 32 + co] = sum;
    }
}

// ---------------------------------------------------------------------------
// K3: stage ys = relu(U+V+K') (interior fast path in packed f16), wB by uint4
// copy of prepacked w2f16, then conv2+relu+conv3 on f16 MFMA. LDS = 39,168 B.
// block 512, grid 64x64.
// ---------------------------------------------------------------------------
__global__ __launch_bounds__(512) void conv_kernel(
    const short* __restrict__ U16, const short* __restrict__ V16,
    const float* __restrict__ Kp, const short* __restrict__ w2f16,
    const float* __restrict__ b2,
    const float* __restrict__ w3, const float* __restrict__ b3,
    float* __restrict__ outp)
{
    __shared__ __attribute__((aligned(16))) short ys[18 * 18 * 32];
    __shared__ __attribute__((aligned(16))) short wB[9 * 32 * 32];

    const int t    = threadIdx.x;
    const int oy0  = blockIdx.y * 16;
    const int ox0  = blockIdx.x * 16;
    const int wid  = t >> 6;
    const int lane = t & 63;
    const int lr   = lane & 15;
    const int lg   = lane >> 4;

    {
        const uint4* src = reinterpret_cast<const uint4*>(w2f16);
        uint4* dst = reinterpret_cast<uint4*>(wB);
        #pragma unroll
        for (int e = t; e < 1152; e += 512)
            dst[e] = src[e];
    }
    const bool interior = (blockIdx.x >= 1) & (blockIdx.x <= 62) &
                          (blockIdx.y >= 1) & (blockIdx.y <= 62);
    if (interior){
        // case (0,0) everywhere; no bounds; packed f16 math; cp thread-invariant
        const int cp = (t & 7) * 4;
        half4 k00;
        {
            float4 kf = *reinterpret_cast<const float4*>(&Kp[cp]);
            k00[0] = (_Float16)kf.x; k00[1] = (_Float16)kf.y;
            k00[2] = (_Float16)kf.z; k00[3] = (_Float16)kf.w;
        }
        #pragma unroll
        for (int pass = 0; pass < 6; ++pass){
            int idx = t + pass * 512;
            if (idx < 2592){
                int po  = idx >> 3;
                int ryo = po / 18;
                int rxo = po - ryo * 18;
                int gy = oy0 - 1 + ryo, gx = ox0 - 1 + rxo;
                half4 u = *reinterpret_cast<const half4*>(&U16[gy * 32 + cp]);
                half4 v = *reinterpret_cast<const half4*>(&V16[gx * 32 + cp]);
                half4 r = u + v + k00;
                #pragma unroll
                for (int e = 0; e < 4; ++e)
                    r[e] = r[e] > (_Float16)0.f ? r[e] : (_Float16)0.f;
                *reinterpret_cast<half4*>(&ys[po * 32 + (cp ^ SWZ(rxo))]) = r;
            }
        }
    } else {
        #pragma unroll
        for (int pass = 0; pass < 6; ++pass){
            int idx = t + pass * 512;
            if (idx < 2592){
                int po  = idx >> 3;
                int cp  = (idx & 7) * 4;
                int ryo = po / 18;
                int rxo = po - ryo * 18;
                int gy = oy0 - 1 + ryo, gx = ox0 - 1 + rxo;
                half4 h = {(_Float16)0.f, (_Float16)0.f, (_Float16)0.f, (_Float16)0.f};
                if ((unsigned)gy < 1024u && (unsigned)gx < 1024u){
                    int yc = (gy == 0) ? 1 : ((gy == 1023) ? 2 : 0);
                    int xc = (gx == 0) ? 1 : ((gx == 1023) ? 2 : 0);
                    half4 u = *reinterpret_cast<const half4*>(
                        &U16[((size_t)(xc << 10) + gy) * 32 + cp]);
                    half4 v = *reinterpret_cast<const half4*>(
                        &V16[((size_t)(yc << 10) + gx) * 32 + cp]);
                    float4 k = *reinterpret_cast<const float4*>(&Kp[(yc * 3 + xc) * 32 + cp]);
                    h[0] = (_Float16)fmaxf((float)u[0] + (float)v[0] + k.x, 0.f);
                    h[1] = (_Float16)fmaxf((float)u[1] + (float)v[1] + k.y, 0.f);
                    h[2] = (_Float16)fmaxf((float)u[2] + (float)v[2] + k.z, 0.f);
                    h[3] = (_Float16)fmaxf((float)u[3] + (float)v[3] + k.w, 0.f);
                }
                *reinterpret_cast<half4*>(&ys[po * 32 + (cp ^ SWZ(rxo))]) = h;
            }
        }
    }
    __syncthreads();

    {
        half8 Bf[2][9];
        float bias[2], w3v[2];
        #pragma unroll
        for (int n = 0; n < 2; ++n){
            int co = n * 16 + lr;
            bias[n] = b2[co];
            w3v[n]  = w3[co];
            #pragma unroll
            for (int tap = 0; tap < 9; ++tap)
                Bf[n][tap] = *reinterpret_cast<const half8*>(
                    &wB[(tap * 32 + co) * 32 + ((lg * 8) ^ SWZ(co))]);
        }
        const float b3v = b3[0];
        for (int s = wid; s < 16; s += 8){
            int p  = s * 16 + lr;
            int ry = p >> 4;
            int rx = p & 15;
            f32x4 acc0 = {0.f, 0.f, 0.f, 0.f};
            f32x4 acc1 = {0.f, 0.f, 0.f, 0.f};
            #pragma unroll
            for (int tap = 0; tap < 9; ++tap){
                const int dy = tap / 3, dx = tap - (tap / 3) * 3;
                int pix = (ry + dy) * 18 + rx + dx;
                half8 A = *reinterpret_cast<const half8*>(
                    &ys[pix * 32 + ((lg * 8) ^ SWZ(rx + dx))]);
                acc0 = __builtin_amdgcn_mfma_f32_16x16x32_f16(A, Bf[0][tap], acc0, 0, 0, 0);
                acc1 = __builtin_amdgcn_mfma_f32_16x16x32_f16(A, Bf[1][tap], acc1, 0, 0, 0);
            }
            float part[4];
            #pragma unroll
            for (int j = 0; j < 4; ++j)
                part[j] = w3v[0] * fmaxf(acc0[j] + bias[0], 0.f)
                        + w3v[1] * fmaxf(acc1[j] + bias[1], 0.f);
            #pragma unroll
            for (int m = 1; m < 16; m <<= 1)
                #pragma unroll
                for (int j = 0; j < 4; ++j)
                    part[j] += __shfl_xor(part[j], m);
            if (lr == 0){
                float4 o = make_float4(part[0] + b3v, part[1] + b3v,
                                       part[2] + b3v, part[3] + b3v);
                *reinterpret_cast<float4*>(outp + (size_t)(oy0 + s) * 1024 + ox0 + lg * 4) = o;
            }
        }
    }
}

// ---------------------------------------------------------------------------
extern "C" void kernel_launch(void* const* d_in, const int* in_sizes, int n_in,
                              void* d_out, int out_size, void* d_ws, size_t ws_size,
                              hipStream_t stream)
{
    const float* lig_nf = (const float*)d_in[0];
    const float* lig_ef = (const float*)d_in[1];
    const float* rec_nf = (const float*)d_in[3];
    const float* rec_ef = (const float*)d_in[4];
    const float* Wn     = (const float*)d_in[6];
    const float* bn     = (const float*)d_in[7];
    const float* We     = (const float*)d_in[8];
    const float* be     = (const float*)d_in[9];
    const float* W_hopi = (const float*)d_in[12];
    const float* b_hopi = (const float*)d_in[13];
    const float* w1     = (const float*)d_in[14];
    const float* b1     = (const float*)d_in[15];
    const float* w2     = (const float*)d_in[16];
    const float* b2     = (const float*)d_in[17];
    const float* w3     = (const float*)d_in[18];
    const float* b3     = (const float*)d_in[19];
    float* outp = (float*)d_out;

    float* part  = (float*)d_ws;                              // [2][16][1024] f32
    float* Kp    = (float*)((char*)d_ws + 393216);            // 3*3*32 f32
    short* U16   = (short*)((char*)d_ws + 394368);            // 3*1024*32 f16
    short* V16   = (short*)((char*)d_ws + 590976);            // 3*1024*32 f16
    short* w2f16 = (short*)((char*)d_ws + 787584);            // 9216 f16 swizzled

    dim3 g1(8, 16, 2);
    gnn_kernel<<<g1, 512, 0, stream>>>(lig_nf, lig_ef, rec_nf, rec_ef,
                                       Wn, We, bn, be, part);
    pp_kernel<<<34, 256, 0, stream>>>(lig_nf, rec_nf, W_hopi, b_hopi,
                                      w1, b1, w2, part, Kp, U16, V16, w2f16);
    dim3 g3(64, 64);
    conv_kernel<<<g3, 512, 0, stream>>>(U16, V16, Kp, w2f16, b2, w3, b3, outp);
}

// Round 16
// 114.938 us; speedup vs baseline: 1.4297x; 1.0259x over previous
//
#include <hip/hip_runtime.h>

// All tensors float32. Math structure exploited:
//  - softmax over axis of size 1 == 1.0 -> attn all-ones, Wa/ba dead.
//  - weighted = row-sum of tanh(agg), broadcast over COLUMNS (N==D quirk).
//  - lig_p = nf@Wl.T + const  ->  x0[h,i,j] = PL[i,h] + PR[j,h] + c[h]
//  - conv1 is LINEAR in rank-structured x0: y1_pre = U[xc][y] + V[yc][x] + K'.
//    conv stages ys = relu(U+V+K'); conv2+conv3 on f16 MFMA.
//  - ROUND-16: pp_kernel was the hidden 47us bottleneck (Occ 1.1%, VALU 1%,
//    latency-bound: 16 serial K-steps x ~7000cyc, no prefetch). P-GEMM role
//    rebuilt on the gnn skeleton: 512 thr, BK=64, DEPTH-2 register prefetch.
//    cveck/w2pack roles adapted to 512 thr. gnn/conv = round-15 verbatim.

typedef _Float16 half8 __attribute__((ext_vector_type(8)));
typedef _Float16 half4 __attribute__((ext_vector_type(4)));
typedef float    f32x4 __attribute__((ext_vector_type(4)));

__device__ __forceinline__ short f2h_bits(float f){
    _Float16 h = (_Float16)f;          // RNE
    return __builtin_bit_cast(short, h);
}
__device__ __forceinline__ half8 pack2(const float4& x, const float4& y){
    half8 r;
    r[0] = (_Float16)x.x; r[1] = (_Float16)x.y;
    r[2] = (_Float16)x.z; r[3] = (_Float16)x.w;
    r[4] = (_Float16)y.x; r[5] = (_Float16)y.y;
    r[6] = (_Float16)y.z; r[7] = (_Float16)y.w;
    return r;
}
__device__ __forceinline__ half4 pack4(const float4& x){
    half4 r;
    r[0] = (_Float16)x.x; r[1] = (_Float16)x.y;
    r[2] = (_Float16)x.z; r[3] = (_Float16)x.w;
    return r;
}
__device__ __forceinline__ float tanh_fast(float x){
    float e = __expf(2.f * x);
    return 1.f - 2.f / (e + 1.f);
}

// ci-block swizzle for conv LDS tiles (round-4 verified layout)
#define SWZ(c) ((((c) >> 1) & 3) << 3)

// ---------------------------------------------------------------------------
// K1 (MFMA): gnn, BM=128/BN=64/BK=64, 512 thr, depth-2 reg prefetch.
// grid (8,16,2). (round-15 verbatim)
// ---------------------------------------------------------------------------
#define GNN_LOAD(AV, BV, KBN) {                                              \
    const int kbn_ = (KBN) & 2047;                                           \
    const float* Asrc_ = (kbn_ < 1024) ? A0 : A1;                            \
    const float* Bsrc_ = (kbn_ < 1024) ? Wn : We;                            \
    const int kk_ = kbn_ & 1023;                                             \
    const float* ap_ = Asrc_ + (size_t)(j0 + arow) * 1024 + kk_ + akc;       \
    const float* bp_ = Bsrc_ + (size_t)(d0 + brow) * 1024 + kk_ + bkc;       \
    AV[0] = *reinterpret_cast<const float4*>(ap_);                           \
    AV[1] = *reinterpret_cast<const float4*>(ap_ + 4);                       \
    AV[2] = *reinterpret_cast<const float4*>(ap_ + 8);                       \
    AV[3] = *reinterpret_cast<const float4*>(ap_ + 12);                      \
    BV[0] = *reinterpret_cast<const float4*>(bp_);                           \
    BV[1] = *reinterpret_cast<const float4*>(bp_ + 4);                       \
}

#define GNN_STAGE(AV, BV) {                                                  \
    const int ga_ = (t & 3) * 2;                                             \
    const int sa_ = arow & 7;                                                \
    *reinterpret_cast<half8*>(&As[arow * 64 + ((ga_    ) ^ sa_) * 8]) = pack2(AV[0], AV[1]); \
    *reinterpret_cast<half8*>(&As[arow * 64 + ((ga_ + 1) ^ sa_) * 8]) = pack2(AV[2], AV[3]); \
    *reinterpret_cast<half8*>(&Bs[brow * 64 + ((t & 7) ^ (brow & 7)) * 8]) = pack2(BV[0], BV[1]); \
}

#define GNN_MFMA() {                                                         \
    _Pragma("unroll")                                                        \
    for (int ks = 0; ks < 2; ++ks){                                          \
        half8 Af[2], Bf[2];                                                  \
        _Pragma("unroll")                                                    \
        for (int m = 0; m < 2; ++m){                                         \
            int row = wm * 32 + m * 16 + lr;                                 \
            int g   = ((ks * 4 + lg) ^ (row & 7)) * 8;                       \
            Af[m] = *reinterpret_cast<const half8*>(&As[row * 64 + g]);      \
        }                                                                    \
        _Pragma("unroll")                                                    \
        for (int n = 0; n < 2; ++n){                                         \
            int col = wn * 32 + n * 16 + lr;                                 \
            int g   = ((ks * 4 + lg) ^ (col & 7)) * 8;                       \
            Bf[n] = *reinterpret_cast<const half8*>(&Bs[col * 64 + g]);      \
        }                                                                    \
        _Pragma("unroll")                                                    \
        for (int m = 0; m < 2; ++m)                                          \
            _Pragma("unroll")                                                \
            for (int n = 0; n < 2; ++n)                                      \
                acc[m][n] = __builtin_amdgcn_mfma_f32_16x16x32_f16(          \
                    Af[m], Bf[n], acc[m][n], 0, 0, 0);                       \
    }                                                                        \
}

__global__ __launch_bounds__(512) void gnn_kernel(
    const float* __restrict__ lig_nf, const float* __restrict__ lig_ef,
    const float* __restrict__ rec_nf, const float* __restrict__ rec_ef,
    const float* __restrict__ Wn, const float* __restrict__ We,
    const float* __restrict__ bn, const float* __restrict__ be,
    float* __restrict__ part)   // [2][16][1024]
{
    __shared__ __attribute__((aligned(16))) short As[128 * 64];
    __shared__ __attribute__((aligned(16))) short Bs[64 * 64];
    __shared__ float red[128][2];

    const int t  = threadIdx.x;
    const int cx = blockIdx.z;
    const float* A0 = cx ? rec_nf : lig_nf;
    const float* A1 = cx ? rec_ef : lig_ef;
    const int j0 = blockIdx.x * 128;
    const int d0 = blockIdx.y * 64;

    const int wid  = t >> 6;
    const int wm   = wid >> 1;
    const int wn   = wid & 1;
    const int lane = t & 63;
    const int lr   = lane & 15;
    const int lg   = lane >> 4;

    f32x4 acc[2][2];
    #pragma unroll
    for (int m = 0; m < 2; ++m)
        #pragma unroll
        for (int n = 0; n < 2; ++n)
            acc[m][n] = (f32x4){0.f, 0.f, 0.f, 0.f};

    const int arow = t >> 2;
    const int akc  = (t & 3) * 16;
    const int brow = t >> 3;
    const int bkc  = (t & 7) * 8;

    float4 avA[4], bvA[2], avB[4], bvB[2];
    GNN_LOAD(avA, bvA, 0);
    GNN_LOAD(avB, bvB, 64);

    for (int kb = 0; kb < 2048; kb += 128){
        __syncthreads();
        GNN_STAGE(avA, bvA);
        GNN_LOAD(avA, bvA, kb + 128);
        __syncthreads();
        GNN_MFMA();
        __syncthreads();
        GNN_STAGE(avB, bvB);
        GNN_LOAD(avB, bvB, kb + 192);
        __syncthreads();
        GNN_MFMA();
    }

    float rowsum[2][4];
    #pragma unroll
    for (int m = 0; m < 2; ++m)
        #pragma unroll
        for (int jj = 0; jj < 4; ++jj) rowsum[m][jj] = 0.f;
    #pragma unroll
    for (int n = 0; n < 2; ++n){
        int d = d0 + wn * 32 + n * 16 + lr;
        float bias = bn[d] + be[d];
        #pragma unroll
        for (int m = 0; m < 2; ++m)
            #pragma unroll
            for (int jj = 0; jj < 4; ++jj)
                rowsum[m][jj] += tanh_fast(acc[m][n][jj] + bias);
    }
    #pragma unroll
    for (int mask = 1; mask < 16; mask <<= 1)
        #pragma unroll
        for (int m = 0; m < 2; ++m)
            #pragma unroll
            for (int jj = 0; jj < 4; ++jj)
                rowsum[m][jj] += __shfl_xor(rowsum[m][jj], mask);
    __syncthreads();
    if (lr == 0){
        #pragma unroll
        for (int m = 0; m < 2; ++m)
            #pragma unroll
            for (int jj = 0; jj < 4; ++jj)
                red[wm * 32 + m * 16 + lg * 4 + jj][wn] = rowsum[m][jj];
    }
    __syncthreads();
    if (t < 128)
        part[(size_t)cx * 16384 + (size_t)blockIdx.y * 1024 + j0 + t]
            = red[t][0] + red[t][1];
}

// ---------------------------------------------------------------------------
// K2: pp_kernel v2. grid 34 x 512 thr.
//  roles 0..31: P GEMM (80-row A-tile incl. halo, BK=64, 16 steps, DEPTH-2
//               register prefetch, waves 0-4 = M-tiles), then uv via MFMA.
//  role 32: cveck -> Kp ; role 33: w2pack -> w2f16  (512-thread adapted)
// ---------------------------------------------------------------------------
#define PP_LOAD(AV, BV, KBN) {                                               \
    const int kcol_ = (KBN) & 1023;                                          \
    _Pragma("unroll")                                                        \
    for (int p = 0; p < 3; ++p){                                             \
        int e_ = t + 512 * p;                                                \
        if (e_ < 1280){                                                      \
            int rowl_ = e_ >> 4;                                             \
            int grow_ = r0 - 8 + rowl_;                                      \
            if ((unsigned)grow_ < 1024u)                                     \
                AV[p] = *reinterpret_cast<const float4*>(                    \
                    nf + (size_t)grow_ * 1024 + kcol_ + (e_ & 15) * 4);      \
            else                                                             \
                AV[p] = make_float4(0.f, 0.f, 0.f, 0.f);                     \
        }                                                                    \
    }                                                                        \
    BV = *reinterpret_cast<const float4*>(                                   \
        W + (size_t)(t >> 4) * 2048 + kcol_ + (t & 15) * 4);                 \
}

#define PP_STAGE(AV, BV) {                                                   \
    _Pragma("unroll")                                                        \
    for (int p = 0; p < 3; ++p){                                             \
        int e_ = t + 512 * p;                                                \
        if (e_ < 1280){                                                      \
            int rowl_ = e_ >> 4;                                             \
            int ga_ = (e_ & 15) >> 1;                                        \
            int sub_ = (e_ & 1) * 4;                                         \
            *reinterpret_cast<half4*>(                                       \
                &As[rowl_ * 64 + ((ga_ ^ (rowl_ & 7)) * 8) + sub_]) = pack4(AV[p]); \
        }                                                                    \
    }                                                                        \
    {                                                                        \
        int row_ = t >> 4;                                                   \
        int ga_ = (t & 15) >> 1;                                             \
        int sub_ = (t & 1) * 4;                                              \
        *reinterpret_cast<half4*>(                                           \
            &Bs[row_ * 64 + ((ga_ ^ (row_ & 7)) * 8) + sub_]) = pack4(BV);   \
    }                                                                        \
}

#define PP_MFMA() {                                                          \
    if (wid < 5){                                                            \
        _Pragma("unroll")                                                    \
        for (int ks = 0; ks < 2; ++ks){                                      \
            int ar_ = wid * 16 + lr;                                         \
            half8 Af = *reinterpret_cast<const half8*>(                      \
                &As[ar_ * 64 + ((ks * 4 + lg) ^ (ar_ & 7)) * 8]);            \
            _Pragma("unroll")                                                \
            for (int n = 0; n < 2; ++n){                                     \
                int col_ = n * 16 + lr;                                      \
                half8 Bf = *reinterpret_cast<const half8*>(                  \
                    &Bs[col_ * 64 + ((ks * 4 + lg) ^ (col_ & 7)) * 8]);      \
                pacc[n] = __builtin_amdgcn_mfma_f32_16x16x32_f16(            \
                    Af, Bf, pacc[n], 0, 0, 0);                               \
            }                                                                \
        }                                                                    \
    }                                                                        \
}

__global__ __launch_bounds__(512) void pp_kernel(
    const float* __restrict__ lig_nf, const float* __restrict__ rec_nf,
    const float* __restrict__ W_hopi, const float* __restrict__ b_hopi,
    const float* __restrict__ w1, const float* __restrict__ b1,
    const float* __restrict__ w2,
    const float* __restrict__ part,
    float* __restrict__ Kp, short* __restrict__ U16, short* __restrict__ V16,
    short* __restrict__ w2f16)
{
    __shared__ __attribute__((aligned(16))) char smem[47232];
    const int t = threadIdx.x;
    const int role = blockIdx.x;

    if (role < 32){
        short* As = reinterpret_cast<short*>(smem);            // 80x64  @0
        short* Bs = reinterpret_cast<short*>(smem + 10240);    // 32x64
        short* Pz = reinterpret_cast<short*>(smem + 14336);    // 80 x stride40
        short* Ws = reinterpret_cast<short*>(smem + 20736);    // 3x32 x stride104

        const int cx = role >> 4;
        const int r0 = (role & 15) * 64;
        const float* nf = cx ? rec_nf : lig_nf;
        const float* W  = W_hopi + (cx ? 1024 : 0);
        short* O = cx ? V16 : U16;

        const int wid = t >> 6;
        const int lane = t & 63;
        const int lr = lane & 15;
        const int lg = lane >> 4;

        // ---- stage Ws[cs][co][k=d*32+ci] (stride 104): tap-subset sums ----
        for (int e = t; e < 9216; e += 512){
            int cs  = e / 3072;
            int rem = e - cs * 3072;
            int co  = rem / 96;
            int k   = rem - co * 96;
            int d   = k >> 5;
            int ci  = k & 31;
            int o_lo = (cs == 1) ? 1 : 0;
            int o_hi = (cs == 2) ? 1 : 2;
            float s = 0.f;
            for (int o = o_lo; o <= o_hi; ++o){
                int tap = cx ? (o * 3 + d) : (d * 3 + o);
                s += w1[co * 288 + ci * 9 + tap];
            }
            Ws[(cs * 32 + co) * 104 + k] = f2h_bits(s);
        }

        // ---- P GEMM: 80 rows x 32 h, K=1024, depth-2 prefetch ----
        f32x4 pacc[2];
        pacc[0] = (f32x4){0.f, 0.f, 0.f, 0.f};
        pacc[1] = (f32x4){0.f, 0.f, 0.f, 0.f};

        float4 avA[3], avB[3];
        float4 bvA, bvB;
        PP_LOAD(avA, bvA, 0);
        PP_LOAD(avB, bvB, 64);

        for (int kb = 0; kb < 1024; kb += 128){
            __syncthreads();
            PP_STAGE(avA, bvA);
            PP_LOAD(avA, bvA, kb + 128);
            __syncthreads();
            PP_MFMA();
            __syncthreads();
            PP_STAGE(avB, bvB);
            PP_LOAD(avB, bvB, kb + 192);
            __syncthreads();
            PP_MFMA();
        }

        // ---- write P (f16) to Pz (stride 40) ----
        if (wid < 5){
            #pragma unroll
            for (int n = 0; n < 2; ++n)
                #pragma unroll
                for (int jj = 0; jj < 4; ++jj){
                    int rowl = wid * 16 + lg * 4 + jj;
                    Pz[rowl * 40 + n * 16 + lr] = f2h_bits(pacc[n][jj]);
                }
        }
        __syncthreads();

        // ---- uv GEMM (waves 0-3): 64 rows x 32 co x K=96 ----
        if (wid < 4){
            f32x4 uacc[3][2];
            #pragma unroll
            for (int cs = 0; cs < 3; ++cs)
                #pragma unroll
                for (int n = 0; n < 2; ++n)
                    uacc[cs][n] = (f32x4){0.f, 0.f, 0.f, 0.f};
            #pragma unroll
            for (int d = 0; d < 3; ++d){
                int ar = wid * 16 + lr;
                half8 Ap = *reinterpret_cast<const half8*>(
                    &Pz[(7 + ar + d) * 40 + lg * 8]);
                #pragma unroll
                for (int cs = 0; cs < 3; ++cs)
                    #pragma unroll
                    for (int n = 0; n < 2; ++n){
                        half8 Bp = *reinterpret_cast<const half8*>(
                            &Ws[(cs * 32 + n * 16 + lr) * 104 + d * 32 + lg * 8]);
                        uacc[cs][n] = __builtin_amdgcn_mfma_f32_16x16x32_f16(
                            Ap, Bp, uacc[cs][n], 0, 0, 0);
                    }
            }
            #pragma unroll
            for (int cs = 0; cs < 3; ++cs)
                #pragma unroll
                for (int n = 0; n < 2; ++n)
                    #pragma unroll
                    for (int jj = 0; jj < 4; ++jj){
                        int grow = r0 + wid * 16 + lg * 4 + jj;
                        O[((size_t)(cs << 10) + grow) * 32 + n * 16 + lr]
                            = f2h_bits(uacc[cs][n][jj]);
                    }
        }
        return;
    }

    if (role == 33){
        // ---------------- w2pack role ----------------
        for (int e = t; e < 9216; e += 512){
            int co  = e / 288;
            int rem = e - co * 288;
            int ci  = rem / 9;
            int tap = rem - ci * 9;
            w2f16[(tap * 32 + co) * 32 + (ci ^ SWZ(co))] = f2h_bits(w2[e]);
        }
        return;
    }

    // ---------------- cveck role (512-thread adaptation) ----------------
    float* ws_l = reinterpret_cast<float*>(smem);              // 4096 B
    float* ws_r = reinterpret_cast<float*>(smem + 4096);       // 4096 B
    float* red  = reinterpret_cast<float*>(smem + 8192);       // 2048 B
    float* cvs  = reinterpret_cast<float*>(smem + 10240);      // 128 B
    float* w1s  = reinterpret_cast<float*>(smem + 10368);      // 36864 B

    #pragma unroll
    for (int q = 0; q < 5; ++q){
        int i4 = t + q * 512;
        if (i4 < 2304)
            *reinterpret_cast<float4*>(&w1s[i4 * 4]) =
                *reinterpret_cast<const float4*>(w1 + i4 * 4);
    }
    for (int j = t; j < 1024; j += 512){
        float sl = 0.f, sr = 0.f;
        #pragma unroll
        for (int b = 0; b < 16; ++b){
            sl += part[b * 1024 + j];
            sr += part[16384 + b * 1024 + j];
        }
        ws_l[j] = sl; ws_r[j] = sr;
    }
    __syncthreads();
    {
        const int h = t & 31;
        const int seg = t >> 5;          // 0..15, 64 j's each
        const float* wl = W_hopi + (size_t)h * 2048 + seg * 64;
        const float* wr = wl + 1024;
        float s = 0.f;
        #pragma unroll 8
        for (int j = 0; j < 64; j += 4){
            float4 a = *reinterpret_cast<const float4*>(wl + j);
            float4 b = *reinterpret_cast<const float4*>(wr + j);
            const float* l = &ws_l[seg * 64 + j];
            const float* r = &ws_r[seg * 64 + j];
            s = fmaf(l[0], a.x, s); s = fmaf(l[1], a.y, s);
            s = fmaf(l[2], a.z, s); s = fmaf(l[3], a.w, s);
            s = fmaf(r[0], b.x, s); s = fmaf(r[1], b.y, s);
            s = fmaf(r[2], b.z, s); s = fmaf(r[3], b.w, s);
        }
        red[t] = s;
    }
    __syncthreads();
    if (t < 32){
        float tot = b_hopi[t];
        #pragma unroll
        for (int g = 0; g < 16; ++g) tot += red[g * 32 + t];
        cvs[t] = tot;
    }
    __syncthreads();
    for (int e = t; e < 288; e += 512){
        int co  = e & 31;
        int cse = e >> 5;
        int yc  = cse / 3, xc = cse - yc * 3;
        float sum = b1[co];
        for (int ci = 0; ci < 32; ++ci){
            const float* wp = &w1s[co * 288 + ci * 9];
            float t00 = wp[0], t01 = wp[1], t02 = wp[2];
            float t10 = wp[3], t11 = wp[4], t12 = wp[5];
            float t20 = wp[6], t21 = wp[7], t22 = wp[8];
            float r0, r1, r2;
            if (xc == 0){ r0 = t00+t01+t02; r1 = t10+t11+t12; r2 = t20+t21+t22; }
            else if (xc == 1){ r0 = t01+t02; r1 = t11+t12; r2 = t21+t22; }
            else { r0 = t00+t01; r1 = t10+t11; r2 = t20+t21; }
            float wsum = (yc == 0) ? (r0+r1+r2) : ((yc == 1) ? (r1+r2) : (r0+r1));
            sum = fmaf(cvs[ci], wsum, sum);
        }
        Kp[cse * 32 + co] = sum;
    }
}

// ---------------------------------------------------------------------------
// K3: stage ys = relu(U+V+K') (interior fast path in packed f16), wB by uint4
// copy of prepacked w2f16, then conv2+relu+conv3 on f16 MFMA. LDS = 39,168 B.
// block 512, grid 64x64. (round-15 verbatim)
// ---------------------------------------------------------------------------
__global__ __launch_bounds__(512) void conv_kernel(
    const short* __restrict__ U16, const short* __restrict__ V16,
    const float* __restrict__ Kp, const short* __restrict__ w2f16,
    const float* __restrict__ b2,
    const float* __restrict__ w3, const float* __restrict__ b3,
    float* __restrict__ outp)
{
    __shared__ __attribute__((aligned(16))) short ys[18 * 18 * 32];
    __shared__ __attribute__((aligned(16))) short wB[9 * 32 * 32];

    const int t    = threadIdx.x;
    const int oy0  = blockIdx.y * 16;
    const int ox0  = blockIdx.x * 16;
    const int wid  = t >> 6;
    const int lane = t & 63;
    const int lr   = lane & 15;
    const int lg   = lane >> 4;

    {
        const uint4* src = reinterpret_cast<const uint4*>(w2f16);
        uint4* dst = reinterpret_cast<uint4*>(wB);
        #pragma unroll
        for (int e = t; e < 1152; e += 512)
            dst[e] = src[e];
    }
    const bool interior = (blockIdx.x >= 1) & (blockIdx.x <= 62) &
                          (blockIdx.y >= 1) & (blockIdx.y <= 62);
    if (interior){
        const int cp = (t & 7) * 4;
        half4 k00;
        {
            float4 kf = *reinterpret_cast<const float4*>(&Kp[cp]);
            k00[0] = (_Float16)kf.x; k00[1] = (_Float16)kf.y;
            k00[2] = (_Float16)kf.z; k00[3] = (_Float16)kf.w;
        }
        #pragma unroll
        for (int pass = 0; pass < 6; ++pass){
            int idx = t + pass * 512;
            if (idx < 2592){
                int po  = idx >> 3;
                int ryo = po / 18;
                int rxo = po - ryo * 18;
                int gy = oy0 - 1 + ryo, gx = ox0 - 1 + rxo;
                half4 u = *reinterpret_cast<const half4*>(&U16[gy * 32 + cp]);
                half4 v = *reinterpret_cast<const half4*>(&V16[gx * 32 + cp]);
                half4 r = u + v + k00;
                #pragma unroll
                for (int e = 0; e < 4; ++e)
                    r[e] = r[e] > (_Float16)0.f ? r[e] : (_Float16)0.f;
                *reinterpret_cast<half4*>(&ys[po * 32 + (cp ^ SWZ(rxo))]) = r;
            }
        }
    } else {
        #pragma unroll
        for (int pass = 0; pass < 6; ++pass){
            int idx = t + pass * 512;
            if (idx < 2592){
                int po  = idx >> 3;
                int cp  = (idx & 7) * 4;
                int ryo = po / 18;
                int rxo = po - ryo * 18;
                int gy = oy0 - 1 + ryo, gx = ox0 - 1 + rxo;
                half4 h = {(_Float16)0.f, (_Float16)0.f, (_Float16)0.f, (_Float16)0.f};
                if ((unsigned)gy < 1024u && (unsigned)gx < 1024u){
                    int yc = (gy == 0) ? 1 : ((gy == 1023) ? 2 : 0);
                    int xc = (gx == 0) ? 1 : ((gx == 1023) ? 2 : 0);
                    half4 u = *reinterpret_cast<const half4*>(
                        &U16[((size_t)(xc << 10) + gy) * 32 + cp]);
                    half4 v = *reinterpret_cast<const half4*>(
                        &V16[((size_t)(yc << 10) + gx) * 32 + cp]);
                    float4 k = *reinterpret_cast<const float4*>(&Kp[(yc * 3 + xc) * 32 + cp]);
                    h[0] = (_Float16)fmaxf((float)u[0] + (float)v[0] + k.x, 0.f);
                    h[1] = (_Float16)fmaxf((float)u[1] + (float)v[1] + k.y, 0.f);
                    h[2] = (_Float16)fmaxf((float)u[2] + (float)v[2] + k.z, 0.f);
                    h[3] = (_Float16)fmaxf((float)u[3] + (float)v[3] + k.w, 0.f);
                }
                *reinterpret_cast<half4*>(&ys[po * 32 + (cp ^ SWZ(rxo))]) = h;
            }
        }
    }
    __syncthreads();

    {
        half8 Bf[2][9];
        float bias[2], w3v[2];
        #pragma unroll
        for (int n = 0; n < 2; ++n){
            int co = n * 16 + lr;
            bias[n] = b2[co];
            w3v[n]  = w3[co];
            #pragma unroll
            for (int tap = 0; tap < 9; ++tap)
                Bf[n][tap] = *reinterpret_cast<const half8*>(
                    &wB[(tap * 32 + co) * 32 + ((lg * 8) ^ SWZ(co))]);
        }
        const float b3v = b3[0];
        for (int s = wid; s < 16; s += 8){
            int p  = s * 16 + lr;
            int ry = p >> 4;
            int rx = p & 15;
            f32x4 acc0 = {0.f, 0.f, 0.f, 0.f};
            f32x4 acc1 = {0.f, 0.f, 0.f, 0.f};
            #pragma unroll
            for (int tap = 0; tap < 9; ++tap){
                const int dy = tap / 3, dx = tap - (tap / 3) * 3;
                int pix = (ry + dy) * 18 + rx + dx;
                half8 A = *reinterpret_cast<const half8*>(
                    &ys[pix * 32 + ((lg * 8) ^ SWZ(rx + dx))]);
                acc0 = __builtin_amdgcn_mfma_f32_16x16x32_f16(A, Bf[0][tap], acc0, 0, 0, 0);
                acc1 = __builtin_amdgcn_mfma_f32_16x16x32_f16(A, Bf[1][tap], acc1, 0, 0, 0);
            }
            float part[4];
            #pragma unroll
            for (int j = 0; j < 4; ++j)
                part[j] = w3v[0] * fmaxf(acc0[j] + bias[0], 0.f)
                        + w3v[1] * fmaxf(acc1[j] + bias[1], 0.f);
            #pragma unroll
            for (int m = 1; m < 16; m <<= 1)
                #pragma unroll
                for (int j = 0; j < 4; ++j)
                    part[j] += __shfl_xor(part[j], m);
            if (lr == 0){
                float4 o = make_float4(part[0] + b3v, part[1] + b3v,
                                       part[2] + b3v, part[3] + b3v);
                *reinterpret_cast<float4*>(outp + (size_t)(oy0 + s) * 1024 + ox0 + lg * 4) = o;
            }
        }
    }
}

// ---------------------------------------------------------------------------
extern "C" void kernel_launch(void* const* d_in, const int* in_sizes, int n_in,
                              void* d_out, int out_size, void* d_ws, size_t ws_size,
                              hipStream_t stream)
{
    const float* lig_nf = (const float*)d_in[0];
    const float* lig_ef = (const float*)d_in[1];
    const float* rec_nf = (const float*)d_in[3];
    const float* rec_ef = (const float*)d_in[4];
    const float* Wn     = (const float*)d_in[6];
    const float* bn     = (const float*)d_in[7];
    const float* We     = (const float*)d_in[8];
    const float* be     = (const float*)d_in[9];
    const float* W_hopi = (const float*)d_in[12];
    const float* b_hopi = (const float*)d_in[13];
    const float* w1     = (const float*)d_in[14];
    const float* b1     = (const float*)d_in[15];
    const float* w2     = (const float*)d_in[16];
    const float* b2     = (const float*)d_in[17];
    const float* w3     = (const float*)d_in[18];
    const float* b3     = (const float*)d_in[19];
    float* outp = (float*)d_out;

    float* part  = (float*)d_ws;                              // [2][16][1024] f32
    float* Kp    = (float*)((char*)d_ws + 393216);            // 3*3*32 f32
    short* U16   = (short*)((char*)d_ws + 394368);            // 3*1024*32 f16
    short* V16   = (short*)((char*)d_ws + 590976);            // 3*1024*32 f16
    short* w2f16 = (short*)((char*)d_ws + 787584);            // 9216 f16 swizzled

    dim3 g1(8, 16, 2);
    gnn_kernel<<<g1, 512, 0, stream>>>(lig_nf, lig_ef, rec_nf, rec_ef,
                                       Wn, We, bn, be, part);
    pp_kernel<<<34, 512, 0, stream>>>(lig_nf, rec_nf, W_hopi, b_hopi,
                                      w1, b1, w2, part, Kp, U16, V16, w2f16);
    dim3 g3(64, 64);
    conv_kernel<<<g3, 512, 0, stream>>>(U16, V16, Kp, w2f16, b2, w3, b3, outp);
}